// Round 7
// baseline (624.204 us; speedup 1.0000x reference)
//
#include <hip/hip_runtime.h>
#include <hip/hip_bf16.h>

#define N_NODES 50000
#define N_EDGES 800000
#define HIDDEN  256
#define N_LAYERS 3
#define N_PAIRS 4096
#define N_LABEL 8192            // 2*N_PAIRS labeled rows
#define NPAD    50176           // 196*256, padded node count for the scan
#define SCAN_BLOCKS (NPAD / 256) // 196

typedef __bf16 bf16x8 __attribute__((ext_vector_type(8)));
typedef __bf16 bf16x4 __attribute__((ext_vector_type(4)));
typedef float  f32x4  __attribute__((ext_vector_type(4)));

__device__ __forceinline__ void load_lds16(const void* g, void* l) {
    __builtin_amdgcn_global_load_lds(
        (const __attribute__((address_space(1))) void*)g,
        (__attribute__((address_space(3))) void*)l, 16, 0, 0);
}

// ---------------------------------------------------------------------------
// MFMA GEMM: C = A @ Wt^T + bias_term.  A bf16 (rows,256), Wt bf16 [n][k].
// 128x128 tile, BK=32, 4 waves x (4x4) 16x16x32 fragments.
//   GATHER_A   : A-rows indirect through idx
//   SCATTER_C  : C-rows indirect through idx (dup-idx writes identical: benign)
//   DEG_BIAS   : bias scaled by deg[node] = offs[node+1]-offs[node]
//   DEG_VIA_IDX: node for deg lookup is idx[row] (A-rows sequential)
//   OUT_BF16   : output dtype
// ---------------------------------------------------------------------------
template <bool GATHER_A, bool SCATTER_C, bool DEG_BIAS, bool DEG_VIA_IDX, bool OUT_BF16>
__global__ __launch_bounds__(256) void mfma_gemm(
    const __bf16* __restrict__ A,
    const __bf16* __restrict__ Wt,    // (256,256) bf16, Wt[n][k]
    const float* __restrict__ bias,   // (256) fp32
    void* __restrict__ Cout,
    const int* __restrict__ idx,
    const int* __restrict__ offs,
    int M)
{
    __shared__ __bf16 As[128 * 32];   // [row][k] 8 KB
    __shared__ __bf16 Bs[128 * 32];   // [n][k]   8 KB
    __shared__ int s_idx[128];

    const int t    = threadIdx.x;
    const int lane = t & 63;
    const int wave = t >> 6;
    const int m0   = blockIdx.x * 128;
    const int n0   = blockIdx.y * 128;

    if constexpr (GATHER_A || SCATTER_C || DEG_VIA_IDX) {
        if (t < 128) s_idx[t] = idx[m0 + t];
        __syncthreads();
    }

    // staging: chunk c = r*256 + t; row = c>>2, col8 = (c&3)*8
    // LDS dest offset = c*16 bytes (wave-uniform base + lane*16: m104-safe)
    const __bf16* aptr[2];
    const __bf16* bptr[2];
    #pragma unroll
    for (int r = 0; r < 2; ++r) {
        const int c    = r * 256 + t;
        const int row  = c >> 2;
        const int col8 = (c & 3) * 8;
        int node;
        if constexpr (GATHER_A) {
            node = s_idx[row];
        } else {
            const int rg = m0 + row;
            node = (rg < M) ? rg : (M - 1);   // clamp; stores guarded below
        }
        aptr[r] = A  + (size_t)node * HIDDEN + col8;
        bptr[r] = Wt + (size_t)(n0 + row) * HIDDEN + col8;
    }

    f32x4 acc[16];
    #pragma unroll
    for (int i = 0; i < 16; ++i) acc[i] = (f32x4){0.f, 0.f, 0.f, 0.f};

    const int wm   = (wave & 1) * 64;
    const int wn   = (wave >> 1) * 64;
    const int fm   = lane & 15;
    const int quad = lane >> 4;

    for (int k0 = 0; k0 < HIDDEN; k0 += 32) {
        __syncthreads();
        #pragma unroll
        for (int r = 0; r < 2; ++r) {
            load_lds16(aptr[r] + k0, (void*)(As + (size_t)(r * 256 + t) * 8));
            load_lds16(bptr[r] + k0, (void*)(Bs + (size_t)(r * 256 + t) * 8));
        }
        __syncthreads();   // drains vmcnt(0): LDS data visible

        bf16x8 af[4], bfr[4];
        #pragma unroll
        for (int mt = 0; mt < 4; ++mt)
            af[mt] = *(const bf16x8*)(As + (wm + mt * 16 + fm) * 32 + quad * 8);
        #pragma unroll
        for (int nt = 0; nt < 4; ++nt)
            bfr[nt] = *(const bf16x8*)(Bs + (wn + nt * 16 + fm) * 32 + quad * 8);

        #pragma unroll
        for (int mt = 0; mt < 4; ++mt)
            #pragma unroll
            for (int nt = 0; nt < 4; ++nt)
                acc[mt * 4 + nt] = __builtin_amdgcn_mfma_f32_16x16x32_bf16(
                    af[mt], bfr[nt], acc[mt * 4 + nt], 0, 0, 0);
    }

    // epilogue: C/D layout col=lane&15, row=quad*4+reg (m89/m91-verified)
    float bb[4];
    #pragma unroll
    for (int nt = 0; nt < 4; ++nt) bb[nt] = bias[n0 + wn + nt * 16 + fm];

    #pragma unroll
    for (int mt = 0; mt < 4; ++mt) {
        const int rbase = wm + mt * 16 + quad * 4;
        #pragma unroll
        for (int rg = 0; rg < 4; ++rg) {
            const int rloc = rbase + rg;
            int orow;
            if constexpr (SCATTER_C) {
                orow = s_idx[rloc];
            } else {
                orow = m0 + rloc;
                if (orow >= M) continue;
            }
            float bscale = 1.f;
            if constexpr (DEG_BIAS) {
                int dnode;
                if constexpr (DEG_VIA_IDX || GATHER_A) dnode = s_idx[rloc];
                else                                   dnode = m0 + rloc;
                bscale = (float)(offs[dnode + 1] - offs[dnode]);
            }
            #pragma unroll
            for (int nt = 0; nt < 4; ++nt) {
                const int col = n0 + wn + nt * 16 + fm;
                const float v = acc[mt * 4 + nt][rg] + bscale * bb[nt];
                if constexpr (OUT_BF16)
                    ((__bf16*)Cout)[(size_t)orow * HIDDEN + col] = (__bf16)v;
                else
                    ((float*)Cout)[(size_t)orow * HIDDEN + col] = v;
            }
        }
    }
}

// ---------------------------------------------------------------------------
// Weight transpose+convert for one layer: T[n][k] = (bf16)W[k][n], 3 tensors.
// ---------------------------------------------------------------------------
__global__ __launch_bounds__(256) void wconv_kernel(
    const float* __restrict__ w0, const float* __restrict__ w1,
    const float* __restrict__ wc,
    __bf16* __restrict__ t0, __bf16* __restrict__ t1, __bf16* __restrict__ tc)
{
    const int z = blockIdx.z;
    const float* W = (z == 0) ? w0 : (z == 1) ? w1 : wc;
    __bf16*      T = (z == 0) ? t0 : (z == 1) ? t1 : tc;

    __shared__ float tile[32][33];
    const int kx = blockIdx.x * 32, nx = blockIdx.y * 32;
    const int tx = threadIdx.x, ty = threadIdx.y;

    for (int i = ty; i < 32; i += 8)
        tile[i][tx] = W[(size_t)(kx + i) * HIDDEN + nx + tx];
    __syncthreads();
    for (int i = ty; i < 32; i += 8)
        T[(size_t)(nx + i) * HIDDEN + kx + tx] = (__bf16)tile[tx][i];
}

// x fp32 -> bf16, 4 elems/thread
__global__ __launch_bounds__(256) void convert_x_kernel(
    const float* __restrict__ x, __bf16* __restrict__ xb)
{
    const size_t i = ((size_t)blockIdx.x * 256 + threadIdx.x) * 4;
    const float4 v = *(const float4*)(x + i);
    bf16x4 o = {(__bf16)v.x, (__bf16)v.y, (__bf16)v.z, (__bf16)v.w};
    *(bf16x4*)(xb + i) = o;
}

// ---------------------------------------------------------------------------
// CSR build: histogram -> 2-level exclusive scan (in-place offs) -> fill
// ---------------------------------------------------------------------------
__global__ __launch_bounds__(256) void hist_kernel(
    const int* __restrict__ dst, int* __restrict__ counts)
{
    int e = blockIdx.x * 256 + threadIdx.x;
    if (e < N_EDGES) atomicAdd(&counts[dst[e]], 1);
}

__device__ __forceinline__ int block_incl_scan(int v, int* s, int t)
{
    s[t] = v; __syncthreads();
    #pragma unroll
    for (int off = 1; off < 256; off <<= 1) {
        int add = (t >= off) ? s[t - off] : 0;
        __syncthreads();
        s[t] += add;
        __syncthreads();
    }
    return s[t];
}

__global__ __launch_bounds__(256) void scan1_kernel(
    const int* __restrict__ counts, int* __restrict__ offs, int* __restrict__ bsum)
{
    __shared__ int s[256];
    const int t = threadIdx.x;
    const int i = blockIdx.x * 256 + t;
    const int v = counts[i];
    int incl = block_incl_scan(v, s, t);
    offs[i] = incl - v;
    if (t == 255) bsum[blockIdx.x] = incl;
}

__global__ __launch_bounds__(256) void scan2_kernel(
    const int* __restrict__ bsum, int* __restrict__ bbase)
{
    __shared__ int s[256];
    const int t = threadIdx.x;
    const int v = (t < SCAN_BLOCKS) ? bsum[t] : 0;
    int incl = block_incl_scan(v, s, t);
    bbase[t] = incl - v;
}

__global__ __launch_bounds__(256) void scan3_kernel(
    int* __restrict__ offs, const int* __restrict__ bbase, int* __restrict__ cursor)
{
    const int i = blockIdx.x * 256 + threadIdx.x;
    const int o = offs[i] + bbase[blockIdx.x];
    offs[i] = o;
    cursor[i] = o;
}

__global__ __launch_bounds__(256) void fill_kernel(
    const int* __restrict__ src, const int* __restrict__ dst,
    int* __restrict__ cursor, int* __restrict__ src_sorted)
{
    int e = blockIdx.x * 256 + threadIdx.x;
    if (e < N_EDGES) {
        int p = atomicAdd(&cursor[dst[e]], 1);
        src_sorted[p] = src[e];
    }
}

// ---------------------------------------------------------------------------
// Column-sliced pull-mode bf16 segment sum (XCD-locality version):
//  - blockIdx.x = slice 0..7 -> 64-byte column slice of each row. With linear
//    round-robin workgroup->XCD dispatch, each XCD touches only 1/8 of x0
//    (3.2 MB, L2-resident) instead of the whole 25.6 MB -> kills the 7x
//    compulsory L2-fill replication seen in R6 (FETCH 177 MB).
//  - 4 waves/block = 4 dst nodes. Per wave: 8 edges in flight (lane>>3 =
//    edge slot), 8 lanes x 8 B cover the 64-B slice.
//  - src ids: one coalesced 64-lane load, shfl broadcast with wave-uniform
//    trip count (all 64 lanes active at every __shfl — R5 lesson).
//  - slot reduction via shfl_xor (no LDS -> no bank conflicts).
// COMPACT: dst nodes from nodelist[], output rows compact in blockIdx order.
// ---------------------------------------------------------------------------
template <bool COMPACT>
__global__ __launch_bounds__(256) void seg_sum3_kernel(
    const __bf16* __restrict__ x0,
    const int* __restrict__ srcs,
    const int* __restrict__ offs,
    const int* __restrict__ nodelist,
    __bf16* __restrict__ out)
{
    const int slice = blockIdx.x;            // 0..7
    const int wave  = threadIdx.x >> 6;
    const int lane  = threadIdx.x & 63;
    const int row   = blockIdx.y * 4 + wave; // dst (or compact) row
    const int d     = COMPACT ? nodelist[row] : row;
    const int slot  = lane >> 3;             // 0..7: edge in flight
    const int li    = lane & 7;              // 8-B piece within 64-B slice
    const int beg   = offs[d];
    const int deg   = offs[d + 1] - beg;

    const __bf16* xs = x0 + slice * 32 + li * 4;

    float a0 = 0.f, a1 = 0.f, a2 = 0.f, a3 = 0.f;
    for (int base = 0; base < deg; base += 64) {
        const int n = min(64, deg - base);   // wave-uniform
        int vs = 0;
        if (base + lane < deg) vs = srcs[beg + base + lane];
        for (int e0 = 0; e0 < n; e0 += 8) {
            const int e = e0 + slot;              // < 64 always
            const int s = __shfl(vs, e);          // all 64 lanes active
            if (e < n) {
                const bf16x4 v = *(const bf16x4*)(xs + (size_t)s * HIDDEN);
                a0 += (float)v[0]; a1 += (float)v[1];
                a2 += (float)v[2]; a3 += (float)v[3];
            }
        }
    }

    // reduce the 8 edge slots (lane bits 3..5); uniform, all lanes active
    #pragma unroll
    for (int m = 8; m <= 32; m <<= 1) {
        a0 += __shfl_xor(a0, m); a1 += __shfl_xor(a1, m);
        a2 += __shfl_xor(a2, m); a3 += __shfl_xor(a3, m);
    }

    if (slot == 0) {
        bf16x4 o = {(__bf16)a0, (__bf16)a1, (__bf16)a2, (__bf16)a3};
        *(bf16x4*)(out + (size_t)row * HIDDEN + slice * 32 + li * 4) = o;
    }
}

extern "C" void kernel_launch(void* const* d_in, const int* in_sizes, int n_in,
                              void* d_out, int out_size, void* d_ws, size_t ws_size,
                              hipStream_t stream)
{
    const float* x       = (const float*)d_in[0];
    const float* f0_w    = (const float*)d_in[1];
    const float* f0_b    = (const float*)d_in[2];
    const float* f1_w    = (const float*)d_in[3];
    const float* f1_b    = (const float*)d_in[4];
    const float* conv_w  = (const float*)d_in[5];
    const float* conv_b  = (const float*)d_in[6];
    const int*   edge_src = (const int*)d_in[7];
    const int*   edge_dst = (const int*)d_in[8];
    const int*   pos      = (const int*)d_in[9];
    float* out = (float*)d_out;

    const size_t buf = (size_t)N_NODES * HIDDEN;   // 12.8M elems

    char* p = (char*)d_ws;
    __bf16* bufA  = (__bf16*)p; p += buf * 2;      // 25.6 MB
    __bf16* bufB  = (__bf16*)p; p += buf * 2;      // 25.6 MB
    __bf16* s_lbl = (__bf16*)p; p += (size_t)N_LABEL * HIDDEN * 2;  // 4 MB
    __bf16* wt0   = (__bf16*)p; p += (size_t)HIDDEN * HIDDEN * 2;
    __bf16* wt1   = (__bf16*)p; p += (size_t)HIDDEN * HIDDEN * 2;
    __bf16* wtc   = (__bf16*)p; p += (size_t)HIDDEN * HIDDEN * 2;
    int* counts     = (int*)p;  p += NPAD * 4;     // reused as cursor
    int* offs       = (int*)p;  p += NPAD * 4;
    int* bsum       = (int*)p;  p += 256 * 4;
    int* bbase      = (int*)p;  p += 256 * 4;
    int* src_sorted = (int*)p;  p += (size_t)N_EDGES * 4;
    int* cursor = counts;       // counts dead after scan1

    const int edge_blocks = (N_EDGES + 255) / 256;   // 3125

    // ---- CSR build (edges layer-invariant) ----
    hipMemsetAsync(counts, 0, NPAD * sizeof(int), stream);
    hist_kernel<<<edge_blocks, 256, 0, stream>>>(edge_dst, counts);
    scan1_kernel<<<SCAN_BLOCKS, 256, 0, stream>>>(counts, offs, bsum);
    scan2_kernel<<<1, 256, 0, stream>>>(bsum, bbase);
    scan3_kernel<<<SCAN_BLOCKS, 256, 0, stream>>>(offs, bbase, cursor);
    fill_kernel<<<edge_blocks, 256, 0, stream>>>(edge_src, edge_dst, cursor, src_sorted);

    // ---- x -> bf16 ----
    convert_x_kernel<<<(int)(buf / 4 / 256), 256, 0, stream>>>(x, bufA);

    const dim3 gemm_grid(391, 2);    // ceil(50000/128) x (256/128)
    const dim3 lbl_grid(64, 2);      // 8192/128 x 2
    const dim3 seg_grid(8, N_NODES / 4);   // (slice, dst-group)
    const dim3 segc_grid(8, N_LABEL / 4);

    __bf16* cur = bufA;              // current x (bf16)
    __bf16* tmp = bufB;

    for (int l = 0; l < N_LAYERS; ++l) {
        const float* W0 = f0_w   + (size_t)l * HIDDEN * HIDDEN;
        const float* B0 = f0_b   + (size_t)l * HIDDEN;
        const float* W1 = f1_w   + (size_t)l * HIDDEN * HIDDEN;
        const float* B1 = f1_b   + (size_t)l * HIDDEN;
        const float* Wc = conv_w + (size_t)l * HIDDEN * HIDDEN;
        const float* Bc = conv_b + (size_t)l * HIDDEN;

        wconv_kernel<<<dim3(8, 8, 3), dim3(32, 8), 0, stream>>>(
            W0, W1, Wc, wt0, wt1, wtc);

        // x0 = x @ F0 + b0  (cur -> tmp)
        mfma_gemm<false, false, false, false, true><<<gemm_grid, 256, 0, stream>>>(
            cur, wt0, B0, tmp, nullptr, nullptr, N_NODES);
        // x0[idx] = x[idx] @ F1 + b1  (cur -> tmp rows)
        mfma_gemm<true, true, false, false, true><<<lbl_grid, 256, 0, stream>>>(
            cur, wt1, B1, tmp, pos, nullptr, N_LABEL);

        if (l < N_LAYERS - 1) {
            // S = segment_sum(x0[src]) at ALL nodes (tmp -> cur)
            seg_sum3_kernel<false><<<seg_grid, 256, 0, stream>>>(
                tmp, src_sorted, offs, nullptr, cur);
            // x_next = S @ Cw + deg*cb  (cur -> tmp), then swap
            mfma_gemm<false, false, true, false, true><<<gemm_grid, 256, 0, stream>>>(
                cur, wtc, Bc, tmp, nullptr, offs, N_NODES);
            __bf16* t2 = cur; cur = tmp; tmp = t2;
        } else {
            // S only at labeled dst nodes (tmp -> s_lbl, compact pos order)
            seg_sum3_kernel<true><<<segc_grid, 256, 0, stream>>>(
                tmp, src_sorted, offs, pos, s_lbl);
            // out[i] = S_lbl[i] @ Cw + deg[pos[i]]*cb  -> d_out (fp32)
            mfma_gemm<false, false, true, true, false><<<lbl_grid, 256, 0, stream>>>(
                s_lbl, wtc, Bc, out, pos, offs, N_LABEL);
        }
    }
}

// Round 9
// 488.959 us; speedup vs baseline: 1.2766x; 1.2766x over previous
//
#include <hip/hip_runtime.h>
#include <hip/hip_bf16.h>

#define N_NODES 50000
#define N_EDGES 800000
#define HIDDEN  256
#define N_LAYERS 3
#define N_PAIRS 4096
#define N_LABEL 8192            // 2*N_PAIRS labeled rows
#define NPAD    50176           // 196*256, padded node count for the scan
#define SCAN_BLOCKS (NPAD / 256) // 196
#define WSZ (HIDDEN * HIDDEN)    // 65536 elems per weight matrix

typedef __bf16 bf16x8 __attribute__((ext_vector_type(8)));
typedef __bf16 bf16x4 __attribute__((ext_vector_type(4)));
typedef float  f32x4  __attribute__((ext_vector_type(4)));

__device__ __forceinline__ void load_lds16(const void* g, void* l) {
    __builtin_amdgcn_global_load_lds(
        (const __attribute__((address_space(1))) void*)g,
        (__attribute__((address_space(3))) void*)l, 16, 0, 0);
}

// ---------------------------------------------------------------------------
// MFMA GEMM: C = A @ Wt^T (+ deg*biasD) (+ biasC).  A bf16 (rows,256),
// Wt bf16 [n][k].  128x128 tile, BK=32, 4 waves x (4x4) 16x16x32 frags.
//   GATHER_A   : A-rows indirect through idx
//   SCATTER_C  : C-rows indirect through idx (dup-idx identical: benign)
//   DEG_BIAS   : add deg[node]*biasD[col], deg = offs[node+1]-offs[node]
//   DEG_VIA_IDX: node for deg lookup is idx[row] (A-rows sequential/compact)
//   HAS_BIAS   : add biasC[col]
//   OUT_BF16   : output dtype
// ---------------------------------------------------------------------------
template <bool GATHER_A, bool SCATTER_C, bool DEG_BIAS, bool DEG_VIA_IDX,
          bool HAS_BIAS, bool OUT_BF16>
__global__ __launch_bounds__(256) void mfma_gemm(
    const __bf16* __restrict__ A,
    const __bf16* __restrict__ Wt,     // (256,256) bf16, Wt[n][k]
    const float* __restrict__ biasD,   // deg-scaled bias (or null)
    const float* __restrict__ biasC,   // plain bias (or null)
    void* __restrict__ Cout,
    const int* __restrict__ idx,
    const int* __restrict__ offs,
    int M)
{
    __shared__ __bf16 As[128 * 32];   // [row][k] 8 KB
    __shared__ __bf16 Bs[128 * 32];   // [n][k]   8 KB
    __shared__ int s_idx[128];

    const int t    = threadIdx.x;
    const int lane = t & 63;
    const int wave = t >> 6;
    const int m0   = blockIdx.x * 128;
    const int n0   = blockIdx.y * 128;

    if constexpr (GATHER_A || SCATTER_C || DEG_VIA_IDX) {
        if (t < 128) s_idx[t] = idx[m0 + t];
        __syncthreads();
    }

    // staging: chunk c = r*256 + t; row = c>>2, col8 = (c&3)*8
    // LDS dest offset = c*16 bytes (wave-uniform base + lane*16: m104-safe)
    const __bf16* aptr[2];
    const __bf16* bptr[2];
    #pragma unroll
    for (int r = 0; r < 2; ++r) {
        const int c    = r * 256 + t;
        const int row  = c >> 2;
        const int col8 = (c & 3) * 8;
        int node;
        if constexpr (GATHER_A) {
            node = s_idx[row];
        } else {
            const int rg = m0 + row;
            node = (rg < M) ? rg : (M - 1);   // clamp; stores guarded below
        }
        aptr[r] = A  + (size_t)node * HIDDEN + col8;
        bptr[r] = Wt + (size_t)(n0 + row) * HIDDEN + col8;
    }

    f32x4 acc[16];
    #pragma unroll
    for (int i = 0; i < 16; ++i) acc[i] = (f32x4){0.f, 0.f, 0.f, 0.f};

    const int wm   = (wave & 1) * 64;
    const int wn   = (wave >> 1) * 64;
    const int fm   = lane & 15;
    const int quad = lane >> 4;

    for (int k0 = 0; k0 < HIDDEN; k0 += 32) {
        __syncthreads();
        #pragma unroll
        for (int r = 0; r < 2; ++r) {
            load_lds16(aptr[r] + k0, (void*)(As + (size_t)(r * 256 + t) * 8));
            load_lds16(bptr[r] + k0, (void*)(Bs + (size_t)(r * 256 + t) * 8));
        }
        __syncthreads();   // drains vmcnt(0): LDS data visible

        bf16x8 af[4], bfr[4];
        #pragma unroll
        for (int mt = 0; mt < 4; ++mt)
            af[mt] = *(const bf16x8*)(As + (wm + mt * 16 + fm) * 32 + quad * 8);
        #pragma unroll
        for (int nt = 0; nt < 4; ++nt)
            bfr[nt] = *(const bf16x8*)(Bs + (wn + nt * 16 + fm) * 32 + quad * 8);

        #pragma unroll
        for (int mt = 0; mt < 4; ++mt)
            #pragma unroll
            for (int nt = 0; nt < 4; ++nt)
                acc[mt * 4 + nt] = __builtin_amdgcn_mfma_f32_16x16x32_bf16(
                    af[mt], bfr[nt], acc[mt * 4 + nt], 0, 0, 0);
    }

    // epilogue: C/D layout col=lane&15, row=quad*4+reg (m89/m91-verified)
    float bd[4], bc[4];
    #pragma unroll
    for (int nt = 0; nt < 4; ++nt) {
        const int col = n0 + wn + nt * 16 + fm;
        bd[nt] = DEG_BIAS ? biasD[col] : 0.f;
        bc[nt] = HAS_BIAS ? biasC[col] : 0.f;
    }

    #pragma unroll
    for (int mt = 0; mt < 4; ++mt) {
        const int rbase = wm + mt * 16 + quad * 4;
        #pragma unroll
        for (int rg = 0; rg < 4; ++rg) {
            const int rloc = rbase + rg;
            int orow;
            if constexpr (SCATTER_C) {
                orow = s_idx[rloc];
            } else {
                orow = m0 + rloc;
                if (orow >= M) continue;
            }
            float bscale = 0.f;
            if constexpr (DEG_BIAS) {
                int dnode;
                if constexpr (DEG_VIA_IDX || GATHER_A) dnode = s_idx[rloc];
                else                                   dnode = m0 + rloc;
                bscale = (float)(offs[dnode + 1] - offs[dnode]);
            }
            #pragma unroll
            for (int nt = 0; nt < 4; ++nt) {
                const int col = n0 + wn + nt * 16 + fm;
                float v = acc[mt * 4 + nt][rg];
                if constexpr (DEG_BIAS) v += bscale * bd[nt];
                if constexpr (HAS_BIAS) v += bc[nt];
                if constexpr (OUT_BF16)
                    ((__bf16*)Cout)[(size_t)orow * HIDDEN + col] = (__bf16)v;
                else
                    ((float*)Cout)[(size_t)orow * HIDDEN + col] = v;
            }
        }
    }
}

// ---------------------------------------------------------------------------
// Weight transpose+convert, ALL 9 tensors: T[z][n][k] = (bf16)W_z[k][n].
// z = layer*3 + {0:F0, 1:F1, 2:Cw}.  grid (8,8,9), block (32,8).
// ---------------------------------------------------------------------------
__global__ __launch_bounds__(256) void wconv_kernel(
    const float* __restrict__ f0_w, const float* __restrict__ f1_w,
    const float* __restrict__ conv_w, __bf16* __restrict__ wt_all)
{
    const int z = blockIdx.z;
    const int layer = z / 3, which = z % 3;
    const float* W = ((which == 0) ? f0_w : (which == 1) ? f1_w : conv_w)
                     + (size_t)layer * WSZ;
    __bf16* T = wt_all + (size_t)z * WSZ;

    __shared__ float tile[32][33];
    const int kx = blockIdx.x * 32, nx = blockIdx.y * 32;
    const int tx = threadIdx.x, ty = threadIdx.y;

    for (int i = ty; i < 32; i += 8)
        tile[i][tx] = W[(size_t)(kx + i) * HIDDEN + nx + tx];
    __syncthreads();
    for (int i = ty; i < 32; i += 8)
        T[(size_t)(nx + i) * HIDDEN + kx + tx] = (__bf16)tile[tx][i];
}

// Straight bf16 convert of conv_w layers 0..1 (NO transpose): the product
// GEMM's B-operand needs row-major Cw[k'][j] (R8 bug: passing Cw^T computed
// F^T·Cw instead of F^T·Cw^T = (Cw·F)^T).
__global__ __launch_bounds__(256) void convert_cw_kernel(
    const float* __restrict__ conv_w, __bf16* __restrict__ cw_nt)
{
    const size_t i = ((size_t)blockIdx.x * 256 + threadIdx.x) * 4;
    const float4 v = *(const float4*)(conv_w + i);
    bf16x4 o = {(__bf16)v.x, (__bf16)v.y, (__bf16)v.z, (__bf16)v.w};
    *(bf16x4*)(cw_nt + i) = o;
}

// ---------------------------------------------------------------------------
// Bias products: q[z][n] = sum_k conv_b[l][k] * W[k][n],
// z = 0..3: (l=0,F0_1),(l=0,F1_1),(l=1,F0_2),(l=1,F1_2).  fp32 exact sources.
// ---------------------------------------------------------------------------
__global__ __launch_bounds__(256) void qprod_kernel(
    const float* __restrict__ conv_b, const float* __restrict__ f0_w,
    const float* __restrict__ f1_w, float* __restrict__ q)
{
    const int z = blockIdx.x;
    const int l = z >> 1, branch = z & 1;
    const float* cb = conv_b + (size_t)l * HIDDEN;
    const float* W  = (branch ? f1_w : f0_w) + (size_t)(l + 1) * WSZ;
    const int n = threadIdx.x;

    float s = 0.f;
    #pragma unroll 4
    for (int k = 0; k < HIDDEN; ++k)
        s += cb[k] * W[(size_t)k * HIDDEN + n];
    q[(size_t)z * HIDDEN + n] = s;
}

// x fp32 -> bf16, 4 elems/thread
__global__ __launch_bounds__(256) void convert_x_kernel(
    const float* __restrict__ x, __bf16* __restrict__ xb)
{
    const size_t i = ((size_t)blockIdx.x * 256 + threadIdx.x) * 4;
    const float4 v = *(const float4*)(x + i);
    bf16x4 o = {(__bf16)v.x, (__bf16)v.y, (__bf16)v.z, (__bf16)v.w};
    *(bf16x4*)(xb + i) = o;
}

// ---------------------------------------------------------------------------
// CSR build: histogram -> 2-level exclusive scan (in-place offs) -> fill
// ---------------------------------------------------------------------------
__global__ __launch_bounds__(256) void hist_kernel(
    const int* __restrict__ dst, int* __restrict__ counts)
{
    int e = blockIdx.x * 256 + threadIdx.x;
    if (e < N_EDGES) atomicAdd(&counts[dst[e]], 1);
}

__device__ __forceinline__ int block_incl_scan(int v, int* s, int t)
{
    s[t] = v; __syncthreads();
    #pragma unroll
    for (int off = 1; off < 256; off <<= 1) {
        int add = (t >= off) ? s[t - off] : 0;
        __syncthreads();
        s[t] += add;
        __syncthreads();
    }
    return s[t];
}

__global__ __launch_bounds__(256) void scan1_kernel(
    const int* __restrict__ counts, int* __restrict__ offs, int* __restrict__ bsum)
{
    __shared__ int s[256];
    const int t = threadIdx.x;
    const int i = blockIdx.x * 256 + t;
    const int v = counts[i];
    int incl = block_incl_scan(v, s, t);
    offs[i] = incl - v;
    if (t == 255) bsum[blockIdx.x] = incl;
}

__global__ __launch_bounds__(256) void scan2_kernel(
    const int* __restrict__ bsum, int* __restrict__ bbase)
{
    __shared__ int s[256];
    const int t = threadIdx.x;
    const int v = (t < SCAN_BLOCKS) ? bsum[t] : 0;
    int incl = block_incl_scan(v, s, t);
    bbase[t] = incl - v;
}

__global__ __launch_bounds__(256) void scan3_kernel(
    int* __restrict__ offs, const int* __restrict__ bbase, int* __restrict__ cursor)
{
    const int i = blockIdx.x * 256 + threadIdx.x;
    const int o = offs[i] + bbase[blockIdx.x];
    offs[i] = o;
    cursor[i] = o;
}

__global__ __launch_bounds__(256) void fill_kernel(
    const int* __restrict__ src, const int* __restrict__ dst,
    int* __restrict__ cursor, int* __restrict__ src_sorted)
{
    int e = blockIdx.x * 256 + threadIdx.x;
    if (e < N_EDGES) {
        int p = atomicAdd(&cursor[dst[e]], 1);
        src_sorted[p] = src[e];
    }
}

// ---------------------------------------------------------------------------
// Pull-mode bf16 segment sum (R6 structure, bank-conflict-free swizzle):
//  - wave loads 64 src ids in ONE coalesced lane-load, broadcasts via __shfl
//    with wave-uniform trip count (all 64 lanes active at every __shfl)
//  - half-wave (32 lanes x 16 B) covers one 512 B row -> 2 rows/wave-load
//  - 8 fp32 partials reduced through LDS with XOR-swizzled indices:
//    store red[p][li*8 + ((k + (li>>2)) & 7)]  -> banks distinct per half-wave
//    read  red[r][(t&248) | (((t&7)+(t>>5))&7)] -> 2-way per wave (free)
// COMPACT: node list from nodelist[], output compact rows (blockIdx order).
// ---------------------------------------------------------------------------
template <bool COMPACT>
__global__ __launch_bounds__(256) void seg_sum2_kernel(
    const __bf16* __restrict__ x0,
    const int* __restrict__ srcs,
    const int* __restrict__ offs,
    const int* __restrict__ nodelist,
    __bf16* __restrict__ out)
{
    __shared__ float red[8][HIDDEN];   // 8 KB
    const int b    = blockIdx.x;
    const int d    = COMPACT ? nodelist[b] : b;
    const int t    = threadIdx.x;
    const int wave = t >> 6;
    const int lane = t & 63;
    const int half = lane >> 5;
    const int li   = lane & 31;
    const int beg  = offs[d];
    const int deg  = offs[d + 1] - beg;

    float a[8];
    #pragma unroll
    for (int k = 0; k < 8; ++k) a[k] = 0.f;

    for (int base = 0; base < deg; base += 64) {
        const int n = min(64, deg - base);   // block-uniform
        int vs = 0;
        if (base + lane < deg) vs = srcs[beg + base + lane];
        // uniform trip count over e0; every lane executes every __shfl
        for (int e0 = 0; e0 < n; e0 += 8) {
            const int e = e0 + 2 * wave + half;       // < 64 always
            const int s = __shfl(vs, e);              // all lanes active
            if (e < n) {
                const bf16x8 v = *(const bf16x8*)(x0 + (size_t)s * HIDDEN + li * 8);
                #pragma unroll
                for (int k = 0; k < 8; ++k) a[k] += (float)v[k];
            }
        }
    }

    const int p = wave * 2 + half;     // partial id 0..7
    #pragma unroll
    for (int k = 0; k < 8; ++k)
        red[p][li * 8 + ((k + (li >> 2)) & 7)] = a[k];   // swizzled store
    __syncthreads();

    const int ridx = (t & 248) | (((t & 7) + (t >> 5)) & 7);  // swizzled read
    float s = 0.f;
    #pragma unroll
    for (int r = 0; r < 8; ++r) s += red[r][ridx];
    out[(size_t)b * HIDDEN + t] = (__bf16)s;
}

extern "C" void kernel_launch(void* const* d_in, const int* in_sizes, int n_in,
                              void* d_out, int out_size, void* d_ws, size_t ws_size,
                              hipStream_t stream)
{
    const float* x       = (const float*)d_in[0];
    const float* f0_w    = (const float*)d_in[1];
    const float* f0_b    = (const float*)d_in[2];
    const float* f1_w    = (const float*)d_in[3];
    const float* f1_b    = (const float*)d_in[4];
    const float* conv_w  = (const float*)d_in[5];
    const float* conv_b  = (const float*)d_in[6];
    const int*   edge_src = (const int*)d_in[7];
    const int*   edge_dst = (const int*)d_in[8];
    const int*   pos      = (const int*)d_in[9];
    float* out = (float*)d_out;

    const size_t buf = (size_t)N_NODES * HIDDEN;   // 12.8M elems

    char* p = (char*)d_ws;
    __bf16* bufA   = (__bf16*)p; p += buf * 2;      // 25.6 MB
    __bf16* bufB   = (__bf16*)p; p += buf * 2;      // 25.6 MB
    __bf16* s_lbl  = (__bf16*)p; p += (size_t)N_LABEL * HIDDEN * 2;  // 4 MB
    __bf16* wt_all = (__bf16*)p; p += (size_t)9 * WSZ * 2;  // 9 transposed W
    __bf16* prod   = (__bf16*)p; p += (size_t)4 * WSZ * 2;  // 4 products
    __bf16* cw_nt  = (__bf16*)p; p += (size_t)2 * WSZ * 2;  // Cw layers 0,1 (no T)
    float*  qv     = (float*)p;  p += (size_t)4 * HIDDEN * 4;
    int* counts     = (int*)p;  p += NPAD * 4;     // reused as cursor
    int* offs       = (int*)p;  p += NPAD * 4;
    int* bsum       = (int*)p;  p += 256 * 4;
    int* bbase      = (int*)p;  p += 256 * 4;
    int* src_sorted = (int*)p;  p += (size_t)N_EDGES * 4;
    int* cursor = counts;       // counts dead after scan1

    const int edge_blocks = (N_EDGES + 255) / 256;   // 3125

    // ---- CSR build (edges layer-invariant) ----
    hipMemsetAsync(counts, 0, NPAD * sizeof(int), stream);
    hist_kernel<<<edge_blocks, 256, 0, stream>>>(edge_dst, counts);
    scan1_kernel<<<SCAN_BLOCKS, 256, 0, stream>>>(counts, offs, bsum);
    scan2_kernel<<<1, 256, 0, stream>>>(bsum, bbase);
    scan3_kernel<<<SCAN_BLOCKS, 256, 0, stream>>>(offs, bbase, cursor);
    fill_kernel<<<edge_blocks, 256, 0, stream>>>(edge_src, edge_dst, cursor, src_sorted);

    // ---- weights: transpose+bf16 all 9, plus straight-bf16 Cw_0/Cw_1 ----
    wconv_kernel<<<dim3(8, 8, 9), dim3(32, 8), 0, stream>>>(
        f0_w, f1_w, conv_w, wt_all);
    convert_cw_kernel<<<(2 * WSZ) / (256 * 4), 256, 0, stream>>>(conv_w, cw_nt);
    qprod_kernel<<<4, 256, 0, stream>>>(conv_b, f0_w, f1_w, qv);

    // products prod_t[z] = (Cw_l · F_{l+1})^T, computed as
    // C[m][k'] = sum_j Ft[m][j] * Cw[k'][j]  (A = F^T, B-operand = row-major Cw)
    const dim3 prod_grid(2, 2);
    for (int z = 0; z < 4; ++z) {
        const int l = z >> 1, branch = z & 1;
        const __bf16* Ft = wt_all + (size_t)((l + 1) * 3 + branch) * WSZ;
        const __bf16* Cw = cw_nt + (size_t)l * WSZ;
        mfma_gemm<false, false, false, false, false, true>
            <<<prod_grid, 256, 0, stream>>>(
            Ft, Cw, nullptr, nullptr, prod + (size_t)z * WSZ,
            nullptr, nullptr, HIDDEN);
    }

    // ---- x -> bf16 ----
    convert_x_kernel<<<(int)(buf / 4 / 256), 256, 0, stream>>>(x, bufA);

    const dim3 gemm_grid(391, 2);    // ceil(50000/128) x (256/128)
    const dim3 lbl_grid(64, 2);      // 8192/128 x 2

    __bf16* cur = bufA;              // current S (bf16); layer0: x itself
    __bf16* tmp = bufB;

    for (int l = 0; l < N_LAYERS; ++l) {
        const float* B0 = f0_b + (size_t)l * HIDDEN;
        const float* B1 = f1_b + (size_t)l * HIDDEN;

        if (l == 0) {
            // x0 = x @ F0_0 + b0
            mfma_gemm<false, false, false, false, true, true>
                <<<gemm_grid, 256, 0, stream>>>(
                cur, wt_all + 0 * WSZ, nullptr, B0, tmp, nullptr, nullptr, N_NODES);
            // x0[idx] = x[idx] @ F1_0 + b1
            mfma_gemm<true, true, false, false, true, true>
                <<<lbl_grid, 256, 0, stream>>>(
                cur, wt_all + 1 * WSZ, nullptr, B1, tmp, pos, nullptr, N_LABEL);
        } else {
            // x0 = S @ (Cw_{l-1}·F0_l) + deg*q0 + b0   (conv folded in)
            const int z0 = (l - 1) * 2;
            mfma_gemm<false, false, true, false, true, true>
                <<<gemm_grid, 256, 0, stream>>>(
                cur, prod + (size_t)z0 * WSZ, qv + (size_t)z0 * HIDDEN, B0,
                tmp, nullptr, offs, N_NODES);
            mfma_gemm<true, true, true, false, true, true>
                <<<lbl_grid, 256, 0, stream>>>(
                cur, prod + (size_t)(z0 + 1) * WSZ, qv + (size_t)(z0 + 1) * HIDDEN,
                B1, tmp, pos, offs, N_LABEL);
        }

        if (l < N_LAYERS - 1) {
            // S = segment_sum(x0[src]) at ALL nodes (tmp -> cur)
            seg_sum2_kernel<false><<<N_NODES, 256, 0, stream>>>(
                tmp, src_sorted, offs, nullptr, cur);
            // cur now holds S_l; next layer's GEMMs consume it directly
        } else {
            // S only at labeled dst nodes (tmp -> s_lbl, compact pos order)
            seg_sum2_kernel<true><<<N_LABEL, 256, 0, stream>>>(
                tmp, src_sorted, offs, pos, s_lbl);
            // out[i] = S_lbl[i] @ Cw_2 + deg[pos[i]]*cb_2  -> d_out (fp32)
            mfma_gemm<false, false, true, true, false, false>
                <<<lbl_grid, 256, 0, stream>>>(
                s_lbl, wt_all + (size_t)(2 * 3 + 2) * WSZ,
                conv_b + (size_t)2 * HIDDEN, nullptr, out, pos, offs, N_LABEL);
        }
    }
}

// Round 10
// 442.163 us; speedup vs baseline: 1.4117x; 1.1058x over previous
//
#include <hip/hip_runtime.h>
#include <hip/hip_bf16.h>

#define N_NODES 50000
#define N_EDGES 800000
#define HIDDEN  256
#define N_LAYERS 3
#define N_PAIRS 4096
#define N_LABEL 8192            // 2*N_PAIRS labeled rows
#define NPAD    50176           // 196*256, padded node count for the scan
#define SCAN_BLOCKS (NPAD / 256) // 196
#define WSZ (HIDDEN * HIDDEN)    // 65536 elems per weight matrix

typedef __bf16 bf16x8 __attribute__((ext_vector_type(8)));
typedef __bf16 bf16x4 __attribute__((ext_vector_type(4)));
typedef float  f32x4  __attribute__((ext_vector_type(4)));

__device__ __forceinline__ void load_lds16(const void* g, void* l) {
    __builtin_amdgcn_global_load_lds(
        (const __attribute__((address_space(1))) void*)g,
        (__attribute__((address_space(3))) void*)l, 16, 0, 0);
}

// ---------------------------------------------------------------------------
// MFMA GEMM: C = A @ Wt^T (+ deg*biasD) (+ biasC).  A bf16 (rows,256),
// Wt bf16 [n][k].  128x128 tile, BK=32, 4 waves x (4x4) 16x16x32 frags.
//   GATHER_A   : A-rows indirect through idx
//   SCATTER_C  : C-rows indirect through idx (dup-idx identical: benign)
//   DEG_BIAS   : add deg[node]*biasD[col], deg = offs[node+1]-offs[node]
//   DEG_VIA_IDX: node for deg lookup is idx[row] (A-rows sequential/compact)
//   HAS_BIAS   : add biasC[col]
//   OUT_BF16   : output dtype
//   PROD_BATCH : weight-product batch mode — blockIdx.z = z in 0..3 selects
//                A = wt_all[(3*(1+(z>>1)) + (z&1))], Wt = cw_nt[z>>1],
//                C = prod[z]  (single launch for all 4 256^3 products)
// ---------------------------------------------------------------------------
template <bool GATHER_A, bool SCATTER_C, bool DEG_BIAS, bool DEG_VIA_IDX,
          bool HAS_BIAS, bool OUT_BF16, bool PROD_BATCH>
__global__ __launch_bounds__(256) void mfma_gemm(
    const __bf16* __restrict__ A_in,
    const __bf16* __restrict__ Wt_in,  // (256,256) bf16, Wt[n][k]
    const float* __restrict__ biasD,   // deg-scaled bias (or null)
    const float* __restrict__ biasC,   // plain bias (or null)
    void* __restrict__ Cout_in,
    const int* __restrict__ idx,
    const int* __restrict__ offs,
    int M)
{
    const __bf16* A  = A_in;
    const __bf16* Wt = Wt_in;
    void* Cout = Cout_in;
    if constexpr (PROD_BATCH) {
        const int z = blockIdx.z;
        A    = A_in  + (size_t)(3 * (1 + (z >> 1)) + (z & 1)) * WSZ;
        Wt   = Wt_in + (size_t)(z >> 1) * WSZ;
        Cout = (void*)((__bf16*)Cout_in + (size_t)z * WSZ);
    }

    __shared__ __bf16 As[128 * 32];   // [row][k] 8 KB
    __shared__ __bf16 Bs[128 * 32];   // [n][k]   8 KB
    __shared__ int s_idx[128];

    const int t    = threadIdx.x;
    const int lane = t & 63;
    const int wave = t >> 6;
    const int m0   = blockIdx.x * 128;
    const int n0   = blockIdx.y * 128;

    if constexpr (GATHER_A || SCATTER_C || DEG_VIA_IDX) {
        if (t < 128) s_idx[t] = idx[m0 + t];
        __syncthreads();
    }

    // staging: chunk c = r*256 + t; row = c>>2, col8 = (c&3)*8
    // LDS dest offset = c*16 bytes (wave-uniform base + lane*16: m104-safe)
    const __bf16* aptr[2];
    const __bf16* bptr[2];
    #pragma unroll
    for (int r = 0; r < 2; ++r) {
        const int c    = r * 256 + t;
        const int row  = c >> 2;
        const int col8 = (c & 3) * 8;
        int node;
        if constexpr (GATHER_A) {
            node = s_idx[row];
        } else {
            const int rg = m0 + row;
            node = (rg < M) ? rg : (M - 1);   // clamp; stores guarded below
        }
        aptr[r] = A  + (size_t)node * HIDDEN + col8;
        bptr[r] = Wt + (size_t)(n0 + row) * HIDDEN + col8;
    }

    f32x4 acc[16];
    #pragma unroll
    for (int i = 0; i < 16; ++i) acc[i] = (f32x4){0.f, 0.f, 0.f, 0.f};

    const int wm   = (wave & 1) * 64;
    const int wn   = (wave >> 1) * 64;
    const int fm   = lane & 15;
    const int quad = lane >> 4;

    for (int k0 = 0; k0 < HIDDEN; k0 += 32) {
        __syncthreads();
        #pragma unroll
        for (int r = 0; r < 2; ++r) {
            load_lds16(aptr[r] + k0, (void*)(As + (size_t)(r * 256 + t) * 8));
            load_lds16(bptr[r] + k0, (void*)(Bs + (size_t)(r * 256 + t) * 8));
        }
        __syncthreads();   // drains vmcnt(0): LDS data visible

        bf16x8 af[4], bfr[4];
        #pragma unroll
        for (int mt = 0; mt < 4; ++mt)
            af[mt] = *(const bf16x8*)(As + (wm + mt * 16 + fm) * 32 + quad * 8);
        #pragma unroll
        for (int nt = 0; nt < 4; ++nt)
            bfr[nt] = *(const bf16x8*)(Bs + (wn + nt * 16 + fm) * 32 + quad * 8);

        #pragma unroll
        for (int mt = 0; mt < 4; ++mt)
            #pragma unroll
            for (int nt = 0; nt < 4; ++nt)
                acc[mt * 4 + nt] = __builtin_amdgcn_mfma_f32_16x16x32_bf16(
                    af[mt], bfr[nt], acc[mt * 4 + nt], 0, 0, 0);
    }

    // epilogue: C/D layout col=lane&15, row=quad*4+reg (m89/m91-verified)
    float bd[4], bc[4];
    #pragma unroll
    for (int nt = 0; nt < 4; ++nt) {
        const int col = n0 + wn + nt * 16 + fm;
        bd[nt] = DEG_BIAS ? biasD[col] : 0.f;
        bc[nt] = HAS_BIAS ? biasC[col] : 0.f;
    }

    #pragma unroll
    for (int mt = 0; mt < 4; ++mt) {
        const int rbase = wm + mt * 16 + quad * 4;
        #pragma unroll
        for (int rg = 0; rg < 4; ++rg) {
            const int rloc = rbase + rg;
            int orow;
            if constexpr (SCATTER_C) {
                orow = s_idx[rloc];
            } else {
                orow = m0 + rloc;
                if (orow >= M) continue;
            }
            float bscale = 0.f;
            if constexpr (DEG_BIAS) {
                int dnode;
                if constexpr (DEG_VIA_IDX || GATHER_A) dnode = s_idx[rloc];
                else                                   dnode = m0 + rloc;
                bscale = (float)(offs[dnode + 1] - offs[dnode]);
            }
            #pragma unroll
            for (int nt = 0; nt < 4; ++nt) {
                const int col = n0 + wn + nt * 16 + fm;
                float v = acc[mt * 4 + nt][rg];
                if constexpr (DEG_BIAS) v += bscale * bd[nt];
                if constexpr (HAS_BIAS) v += bc[nt];
                if constexpr (OUT_BF16)
                    ((__bf16*)Cout)[(size_t)orow * HIDDEN + col] = (__bf16)v;
                else
                    ((float*)Cout)[(size_t)orow * HIDDEN + col] = v;
            }
        }
    }
}

// ---------------------------------------------------------------------------
// Weight transpose+convert, ALL 9 tensors: T[z][n][k] = (bf16)W_z[k][n].
// z = layer*3 + {0:F0, 1:F1, 2:Cw}.  grid (8,8,9), block (32,8).
// ---------------------------------------------------------------------------
__global__ __launch_bounds__(256) void wconv_kernel(
    const float* __restrict__ f0_w, const float* __restrict__ f1_w,
    const float* __restrict__ conv_w, __bf16* __restrict__ wt_all)
{
    const int z = blockIdx.z;
    const int layer = z / 3, which = z % 3;
    const float* W = ((which == 0) ? f0_w : (which == 1) ? f1_w : conv_w)
                     + (size_t)layer * WSZ;
    __bf16* T = wt_all + (size_t)z * WSZ;

    __shared__ float tile[32][33];
    const int kx = blockIdx.x * 32, nx = blockIdx.y * 32;
    const int tx = threadIdx.x, ty = threadIdx.y;

    for (int i = ty; i < 32; i += 8)
        tile[i][tx] = W[(size_t)(kx + i) * HIDDEN + nx + tx];
    __syncthreads();
    for (int i = ty; i < 32; i += 8)
        T[(size_t)(nx + i) * HIDDEN + kx + tx] = (__bf16)tile[tx][i];
}

// Straight bf16 convert of conv_w layers 0..1 (NO transpose): the product
// GEMM's B-operand needs row-major Cw[k'][j] so that C = F^T·Cw^T = (Cw·F)^T.
__global__ __launch_bounds__(256) void convert_cw_kernel(
    const float* __restrict__ conv_w, __bf16* __restrict__ cw_nt)
{
    const size_t i = ((size_t)blockIdx.x * 256 + threadIdx.x) * 4;
    const float4 v = *(const float4*)(conv_w + i);
    bf16x4 o = {(__bf16)v.x, (__bf16)v.y, (__bf16)v.z, (__bf16)v.w};
    *(bf16x4*)(cw_nt + i) = o;
}

// ---------------------------------------------------------------------------
// Bias products: q[z][n] = sum_k conv_b[l][k] * W[k][n], k-split 4 ways for
// parallelism (grid 16; qv pre-zeroed; fp32 atomics, deterministic enough).
// z = 0..3: (l=0,F0_1),(l=0,F1_1),(l=1,F0_2),(l=1,F1_2).
// ---------------------------------------------------------------------------
__global__ __launch_bounds__(256) void qprod_kernel(
    const float* __restrict__ conv_b, const float* __restrict__ f0_w,
    const float* __restrict__ f1_w, float* __restrict__ q)
{
    const int z = blockIdx.x >> 2;
    const int kq = blockIdx.x & 3;
    const int l = z >> 1, branch = z & 1;
    const float* cb = conv_b + (size_t)l * HIDDEN;
    const float* W  = (branch ? f1_w : f0_w) + (size_t)(l + 1) * WSZ;
    const int n = threadIdx.x;

    float s = 0.f;
    #pragma unroll 4
    for (int k = kq * 64; k < kq * 64 + 64; ++k)
        s += cb[k] * W[(size_t)k * HIDDEN + n];
    atomicAdd(&q[(size_t)z * HIDDEN + n], s);
}

// x fp32 -> bf16, 4 elems/thread
__global__ __launch_bounds__(256) void convert_x_kernel(
    const float* __restrict__ x, __bf16* __restrict__ xb)
{
    const size_t i = ((size_t)blockIdx.x * 256 + threadIdx.x) * 4;
    const float4 v = *(const float4*)(x + i);
    bf16x4 o = {(__bf16)v.x, (__bf16)v.y, (__bf16)v.z, (__bf16)v.w};
    *(bf16x4*)(xb + i) = o;
}

// ---------------------------------------------------------------------------
// CSR build: histogram -> 2-level exclusive scan (in-place offs) -> fill
// ---------------------------------------------------------------------------
__global__ __launch_bounds__(256) void hist_kernel(
    const int* __restrict__ dst, int* __restrict__ counts)
{
    int e = blockIdx.x * 256 + threadIdx.x;
    if (e < N_EDGES) atomicAdd(&counts[dst[e]], 1);
}

__device__ __forceinline__ int block_incl_scan(int v, int* s, int t)
{
    s[t] = v; __syncthreads();
    #pragma unroll
    for (int off = 1; off < 256; off <<= 1) {
        int add = (t >= off) ? s[t - off] : 0;
        __syncthreads();
        s[t] += add;
        __syncthreads();
    }
    return s[t];
}

__global__ __launch_bounds__(256) void scan1_kernel(
    const int* __restrict__ counts, int* __restrict__ offs, int* __restrict__ bsum)
{
    __shared__ int s[256];
    const int t = threadIdx.x;
    const int i = blockIdx.x * 256 + t;
    const int v = counts[i];
    int incl = block_incl_scan(v, s, t);
    offs[i] = incl - v;
    if (t == 255) bsum[blockIdx.x] = incl;
}

__global__ __launch_bounds__(256) void scan2_kernel(
    const int* __restrict__ bsum, int* __restrict__ bbase)
{
    __shared__ int s[256];
    const int t = threadIdx.x;
    const int v = (t < SCAN_BLOCKS) ? bsum[t] : 0;
    int incl = block_incl_scan(v, s, t);
    bbase[t] = incl - v;
}

__global__ __launch_bounds__(256) void scan3_kernel(
    int* __restrict__ offs, const int* __restrict__ bbase, int* __restrict__ cursor)
{
    const int i = blockIdx.x * 256 + threadIdx.x;
    const int o = offs[i] + bbase[blockIdx.x];
    offs[i] = o;
    cursor[i] = o;
}

__global__ __launch_bounds__(256) void fill_kernel(
    const int* __restrict__ src, const int* __restrict__ dst,
    int* __restrict__ cursor, int* __restrict__ src_sorted)
{
    int e = blockIdx.x * 256 + threadIdx.x;
    if (e < N_EDGES) {
        int p = atomicAdd(&cursor[dst[e]], 1);
        src_sorted[p] = src[e];
    }
}

// ---------------------------------------------------------------------------
// Pull-mode bf16 segment sum v4 — half-wave-per-dst, zero LDS, MLP-unrolled:
//  - each HALF-WAVE (32 lanes x 16 B = full 512 B row) owns one dst node:
//    no partials, no LDS reduce, direct bf16x8 store. 8 dsts per 256-block.
//  - src ids: each half loads 32 ids coalesced, broadcasts via __shfl from
//    ITS OWN half (source lane active even when the two halves' loop trip
//    counts diverge — R5 lesson applies per-half here).
//  - inner loop unrolled x4: 4 independent row-loads in flight per half-wave
//    (~32/block, ~256/CU) to cover the ~400-cyc mixed L2/HBM latency that
//    capped R9's block-per-dst version at 2.7 TB/s.
// COMPACT: node list from nodelist[], output compact rows.
// ---------------------------------------------------------------------------
template <bool COMPACT>
__global__ __launch_bounds__(256) void seg_sum4_kernel(
    const __bf16* __restrict__ x0,
    const int* __restrict__ srcs,
    const int* __restrict__ offs,
    const int* __restrict__ nodelist,
    __bf16* __restrict__ out)
{
    const int t    = threadIdx.x;
    const int wave = t >> 6;
    const int lane = t & 63;
    const int half = lane >> 5;
    const int li   = lane & 31;
    const int row  = blockIdx.x * 8 + wave * 2 + half;
    const int d    = COMPACT ? nodelist[row] : row;
    const int beg  = offs[d];
    const int deg  = offs[d + 1] - beg;
    const int hb   = half * 32;            // shfl base lane of this half

    const __bf16* xs = x0 + li * 8;        // this lane's 16-B column piece

    float a[8];
    #pragma unroll
    for (int k = 0; k < 8; ++k) a[k] = 0.f;

    for (int base = 0; base < deg; base += 32) {
        const int n = min(32, deg - base);             // half-uniform
        int vs = 0;
        if (li < n) vs = srcs[beg + base + li];
        int j = 0;
        for (; j + 4 <= n; j += 4) {                   // 4 loads in flight
            const int s0 = __shfl(vs, hb + j + 0);
            const int s1 = __shfl(vs, hb + j + 1);
            const int s2 = __shfl(vs, hb + j + 2);
            const int s3 = __shfl(vs, hb + j + 3);
            const bf16x8 v0 = *(const bf16x8*)(xs + (size_t)s0 * HIDDEN);
            const bf16x8 v1 = *(const bf16x8*)(xs + (size_t)s1 * HIDDEN);
            const bf16x8 v2 = *(const bf16x8*)(xs + (size_t)s2 * HIDDEN);
            const bf16x8 v3 = *(const bf16x8*)(xs + (size_t)s3 * HIDDEN);
            #pragma unroll
            for (int k = 0; k < 8; ++k)
                a[k] += (float)v0[k] + (float)v1[k] + (float)v2[k] + (float)v3[k];
        }
        for (; j < n; ++j) {
            const int s = __shfl(vs, hb + j);
            const bf16x8 v = *(const bf16x8*)(xs + (size_t)s * HIDDEN);
            #pragma unroll
            for (int k = 0; k < 8; ++k) a[k] += (float)v[k];
        }
    }

    bf16x8 o;
    #pragma unroll
    for (int k = 0; k < 8; ++k) o[k] = (__bf16)a[k];
    *(bf16x8*)(out + (size_t)row * HIDDEN + li * 8) = o;
}

extern "C" void kernel_launch(void* const* d_in, const int* in_sizes, int n_in,
                              void* d_out, int out_size, void* d_ws, size_t ws_size,
                              hipStream_t stream)
{
    const float* x       = (const float*)d_in[0];
    const float* f0_w    = (const float*)d_in[1];
    const float* f0_b    = (const float*)d_in[2];
    const float* f1_w    = (const float*)d_in[3];
    const float* f1_b    = (const float*)d_in[4];
    const float* conv_w  = (const float*)d_in[5];
    const float* conv_b  = (const float*)d_in[6];
    const int*   edge_src = (const int*)d_in[7];
    const int*   edge_dst = (const int*)d_in[8];
    const int*   pos      = (const int*)d_in[9];
    float* out = (float*)d_out;

    const size_t buf = (size_t)N_NODES * HIDDEN;   // 12.8M elems

    char* p = (char*)d_ws;
    __bf16* bufA   = (__bf16*)p; p += buf * 2;      // 25.6 MB
    __bf16* bufB   = (__bf16*)p; p += buf * 2;      // 25.6 MB
    __bf16* s_lbl  = (__bf16*)p; p += (size_t)N_LABEL * HIDDEN * 2;  // 4 MB
    __bf16* wt_all = (__bf16*)p; p += (size_t)9 * WSZ * 2;  // 9 transposed W
    __bf16* prod   = (__bf16*)p; p += (size_t)4 * WSZ * 2;  // 4 products
    __bf16* cw_nt  = (__bf16*)p; p += (size_t)2 * WSZ * 2;  // Cw layers 0,1 (no T)
    float*  qv     = (float*)p;  p += (size_t)4 * HIDDEN * 4;
    int* counts     = (int*)p;  p += NPAD * 4;     // reused as cursor
    int* offs       = (int*)p;  p += NPAD * 4;
    int* bsum       = (int*)p;  p += 256 * 4;
    int* bbase      = (int*)p;  p += 256 * 4;
    int* src_sorted = (int*)p;  p += (size_t)N_EDGES * 4;
    int* cursor = counts;       // counts dead after scan1

    const int edge_blocks = (N_EDGES + 255) / 256;   // 3125

    // ---- CSR build (edges layer-invariant) ----
    hipMemsetAsync(counts, 0, NPAD * sizeof(int), stream);
    hist_kernel<<<edge_blocks, 256, 0, stream>>>(edge_dst, counts);
    scan1_kernel<<<SCAN_BLOCKS, 256, 0, stream>>>(counts, offs, bsum);
    scan2_kernel<<<1, 256, 0, stream>>>(bsum, bbase);
    scan3_kernel<<<SCAN_BLOCKS, 256, 0, stream>>>(offs, bbase, cursor);
    fill_kernel<<<edge_blocks, 256, 0, stream>>>(edge_src, edge_dst, cursor, src_sorted);

    // ---- weights: transpose+bf16 all 9, straight-bf16 Cw_0/Cw_1, fold ----
    wconv_kernel<<<dim3(8, 8, 9), dim3(32, 8), 0, stream>>>(
        f0_w, f1_w, conv_w, wt_all);
    convert_cw_kernel<<<(2 * WSZ) / (256 * 4), 256, 0, stream>>>(conv_w, cw_nt);
    hipMemsetAsync(qv, 0, 4 * HIDDEN * sizeof(float), stream);
    qprod_kernel<<<16, 256, 0, stream>>>(conv_b, f0_w, f1_w, qv);

    // all 4 products prod_t[z] = (Cw_l · F_{l+1})^T in ONE batched launch
    mfma_gemm<false, false, false, false, false, true, true>
        <<<dim3(2, 2, 4), 256, 0, stream>>>(
        wt_all, cw_nt, nullptr, nullptr, prod, nullptr, nullptr, HIDDEN);

    // ---- x -> bf16 ----
    convert_x_kernel<<<(int)(buf / 4 / 256), 256, 0, stream>>>(x, bufA);

    const dim3 gemm_grid(391, 2);    // ceil(50000/128) x (256/128)
    const dim3 lbl_grid(64, 2);      // 8192/128 x 2

    __bf16* cur = bufA;              // current S (bf16); layer0: x itself
    __bf16* tmp = bufB;

    for (int l = 0; l < N_LAYERS; ++l) {
        const float* B0 = f0_b + (size_t)l * HIDDEN;
        const float* B1 = f1_b + (size_t)l * HIDDEN;

        if (l == 0) {
            // x0 = x @ F0_0 + b0
            mfma_gemm<false, false, false, false, true, true, false>
                <<<gemm_grid, 256, 0, stream>>>(
                cur, wt_all + 0 * WSZ, nullptr, B0, tmp, nullptr, nullptr, N_NODES);
            // x0[idx] = x[idx] @ F1_0 + b1
            mfma_gemm<true, true, false, false, true, true, false>
                <<<lbl_grid, 256, 0, stream>>>(
                cur, wt_all + 1 * WSZ, nullptr, B1, tmp, pos, nullptr, N_LABEL);
        } else {
            // x0 = S @ (Cw_{l-1}·F0_l) + deg*q0 + b0   (conv folded in)
            const int z0 = (l - 1) * 2;
            mfma_gemm<false, false, true, false, true, true, false>
                <<<gemm_grid, 256, 0, stream>>>(
                cur, prod + (size_t)z0 * WSZ, qv + (size_t)z0 * HIDDEN, B0,
                tmp, nullptr, offs, N_NODES);
            mfma_gemm<true, true, true, false, true, true, false>
                <<<lbl_grid, 256, 0, stream>>>(
                cur, prod + (size_t)(z0 + 1) * WSZ, qv + (size_t)(z0 + 1) * HIDDEN,
                B1, tmp, pos, offs, N_LABEL);
        }

        if (l < N_LAYERS - 1) {
            // S = segment_sum(x0[src]) at ALL nodes (tmp -> cur)
            seg_sum4_kernel<false><<<N_NODES / 8, 256, 0, stream>>>(
                tmp, src_sorted, offs, nullptr, cur);
        } else {
            // S only at labeled dst nodes (tmp -> s_lbl, compact pos order)
            seg_sum4_kernel<true><<<N_LABEL / 8, 256, 0, stream>>>(
                tmp, src_sorted, offs, pos, s_lbl);
            // out[i] = S_lbl[i] @ Cw_2 + deg[pos[i]]*cb_2  -> d_out (fp32)
            mfma_gemm<false, false, true, true, false, false, false>
                <<<lbl_grid, 256, 0, stream>>>(
                s_lbl, wt_all + (size_t)(2 * 3 + 2) * WSZ,
                conv_b + (size_t)2 * HIDDEN, nullptr, out, pos, offs, N_LABEL);
        }
    }
}

// Round 11
// 437.969 us; speedup vs baseline: 1.4252x; 1.0096x over previous
//
#include <hip/hip_runtime.h>
#include <hip/hip_bf16.h>

#define N_NODES 50000
#define N_EDGES 800000
#define HIDDEN  256
#define N_LAYERS 3
#define N_PAIRS 4096
#define N_LABEL 8192            // 2*N_PAIRS labeled rows
#define NPAD    50176           // 196*256, padded node count for the scan
#define SCAN_BLOCKS (NPAD / 256) // 196
#define WSZ (HIDDEN * HIDDEN)    // 65536 elems per weight matrix

typedef __bf16 bf16x8 __attribute__((ext_vector_type(8)));
typedef __bf16 bf16x4 __attribute__((ext_vector_type(4)));
typedef float  f32x4  __attribute__((ext_vector_type(4)));

__device__ __forceinline__ void load_lds16(const void* g, void* l) {
    __builtin_amdgcn_global_load_lds(
        (const __attribute__((address_space(1))) void*)g,
        (__attribute__((address_space(3))) void*)l, 16, 0, 0);
}

// ---------------------------------------------------------------------------
// MFMA GEMM: C = A @ Wt^T (+ deg*biasD) (+ biasC).  Wt bf16 [n][k].
// 128x128 tile, BK=32, 4 waves x (4x4) 16x16x32 frags.
//   GATHER_A   : A-rows indirect through idx
//   SCATTER_C  : C-rows indirect through idx (dup-idx identical: benign)
//   DEG_BIAS   : add deg[node]*biasD[col], deg = offs[node+1]-offs[node]
//   DEG_VIA_IDX: node for deg lookup is idx[row] (A-rows sequential/compact)
//   HAS_BIAS   : add biasC[col]
//   OUT_BF16   : output dtype
//   PROD_BATCH : blockIdx.z = z in 0..3 selects the 4 weight-product GEMMs
//   A_FP32     : A is fp32; stage via f32 loads + in-reg bf16 convert +
//                ds_write (fuses the x->bf16 conversion into layer-0 GEMMs)
// ---------------------------------------------------------------------------
template <bool GATHER_A, bool SCATTER_C, bool DEG_BIAS, bool DEG_VIA_IDX,
          bool HAS_BIAS, bool OUT_BF16, bool PROD_BATCH, bool A_FP32>
__global__ __launch_bounds__(256) void mfma_gemm(
    const void* __restrict__ A_in,     // bf16 or fp32 per A_FP32
    const __bf16* __restrict__ Wt_in,  // (256,256) bf16, Wt[n][k]
    const float* __restrict__ biasD,   // deg-scaled bias (or null)
    const float* __restrict__ biasC,   // plain bias (or null)
    void* __restrict__ Cout_in,
    const int* __restrict__ idx,
    const int* __restrict__ offs,
    int M)
{
    const __bf16* A  = (const __bf16*)A_in;
    const float*  A32 = (const float*)A_in;
    const __bf16* Wt = Wt_in;
    void* Cout = Cout_in;
    if constexpr (PROD_BATCH) {
        const int z = blockIdx.z;
        A    = (const __bf16*)A_in + (size_t)(3 * (1 + (z >> 1)) + (z & 1)) * WSZ;
        Wt   = Wt_in + (size_t)(z >> 1) * WSZ;
        Cout = (void*)((__bf16*)Cout_in + (size_t)z * WSZ);
    }

    __shared__ __bf16 As[128 * 32];   // [row][k] 8 KB
    __shared__ __bf16 Bs[128 * 32];   // [n][k]   8 KB
    __shared__ int s_idx[128];

    const int t    = threadIdx.x;
    const int lane = t & 63;
    const int wave = t >> 6;
    const int m0   = blockIdx.x * 128;
    const int n0   = blockIdx.y * 128;

    if constexpr (GATHER_A || SCATTER_C || DEG_VIA_IDX) {
        if (t < 128) s_idx[t] = idx[m0 + t];
        __syncthreads();
    }

    // staging: chunk c = r*256 + t; row = c>>2, col8 = (c&3)*8
    // LDS dest offset = c*16 bytes (wave-uniform base + lane*16: m104-safe)
    const __bf16* aptr[2];
    const float*  aptr32[2];
    const __bf16* bptr[2];
    #pragma unroll
    for (int r = 0; r < 2; ++r) {
        const int c    = r * 256 + t;
        const int row  = c >> 2;
        const int col8 = (c & 3) * 8;
        int node;
        if constexpr (GATHER_A) {
            node = s_idx[row];
        } else {
            const int rg = m0 + row;
            node = (rg < M) ? rg : (M - 1);   // clamp; stores guarded below
        }
        if constexpr (A_FP32) aptr32[r] = A32 + (size_t)node * HIDDEN + col8;
        else                  aptr[r]   = A   + (size_t)node * HIDDEN + col8;
        bptr[r] = Wt + (size_t)(n0 + row) * HIDDEN + col8;
    }

    f32x4 acc[16];
    #pragma unroll
    for (int i = 0; i < 16; ++i) acc[i] = (f32x4){0.f, 0.f, 0.f, 0.f};

    const int wm   = (wave & 1) * 64;
    const int wn   = (wave >> 1) * 64;
    const int fm   = lane & 15;
    const int quad = lane >> 4;

    for (int k0 = 0; k0 < HIDDEN; k0 += 32) {
        __syncthreads();
        #pragma unroll
        for (int r = 0; r < 2; ++r) {
            if constexpr (A_FP32) {
                const float* ap = aptr32[r] + k0;
                const float4 u0 = *(const float4*)(ap);
                const float4 u1 = *(const float4*)(ap + 4);
                bf16x8 w = {(__bf16)u0.x, (__bf16)u0.y, (__bf16)u0.z, (__bf16)u0.w,
                            (__bf16)u1.x, (__bf16)u1.y, (__bf16)u1.z, (__bf16)u1.w};
                *(bf16x8*)(As + (size_t)(r * 256 + t) * 8) = w;
            } else {
                load_lds16(aptr[r] + k0, (void*)(As + (size_t)(r * 256 + t) * 8));
            }
            load_lds16(bptr[r] + k0, (void*)(Bs + (size_t)(r * 256 + t) * 8));
        }
        __syncthreads();   // drains vmcnt+lgkmcnt: staged data visible

        bf16x8 af[4], bfr[4];
        #pragma unroll
        for (int mt = 0; mt < 4; ++mt)
            af[mt] = *(const bf16x8*)(As + (wm + mt * 16 + fm) * 32 + quad * 8);
        #pragma unroll
        for (int nt = 0; nt < 4; ++nt)
            bfr[nt] = *(const bf16x8*)(Bs + (wn + nt * 16 + fm) * 32 + quad * 8);

        #pragma unroll
        for (int mt = 0; mt < 4; ++mt)
            #pragma unroll
            for (int nt = 0; nt < 4; ++nt)
                acc[mt * 4 + nt] = __builtin_amdgcn_mfma_f32_16x16x32_bf16(
                    af[mt], bfr[nt], acc[mt * 4 + nt], 0, 0, 0);
    }

    // epilogue: C/D layout col=lane&15, row=quad*4+reg (m89/m91-verified)
    float bd[4], bc[4];
    #pragma unroll
    for (int nt = 0; nt < 4; ++nt) {
        const int col = n0 + wn + nt * 16 + fm;
        bd[nt] = DEG_BIAS ? biasD[col] : 0.f;
        bc[nt] = HAS_BIAS ? biasC[col] : 0.f;
    }

    #pragma unroll
    for (int mt = 0; mt < 4; ++mt) {
        const int rbase = wm + mt * 16 + quad * 4;
        #pragma unroll
        for (int rg = 0; rg < 4; ++rg) {
            const int rloc = rbase + rg;
            int orow;
            if constexpr (SCATTER_C) {
                orow = s_idx[rloc];
            } else {
                orow = m0 + rloc;
                if (orow >= M) continue;
            }
            float bscale = 0.f;
            if constexpr (DEG_BIAS) {
                int dnode;
                if constexpr (DEG_VIA_IDX || GATHER_A) dnode = s_idx[rloc];
                else                                   dnode = m0 + rloc;
                bscale = (float)(offs[dnode + 1] - offs[dnode]);
            }
            #pragma unroll
            for (int nt = 0; nt < 4; ++nt) {
                const int col = n0 + wn + nt * 16 + fm;
                float v = acc[mt * 4 + nt][rg];
                if constexpr (DEG_BIAS) v += bscale * bd[nt];
                if constexpr (HAS_BIAS) v += bc[nt];
                if constexpr (OUT_BF16)
                    ((__bf16*)Cout)[(size_t)orow * HIDDEN + col] = (__bf16)v;
                else
                    ((float*)Cout)[(size_t)orow * HIDDEN + col] = v;
            }
        }
    }
}

// ---------------------------------------------------------------------------
// Weight prep, 11 z-slices in ONE launch:
//  z 0..8 : T[z][n][k] = (bf16)W_z[k][n]   (transpose; z = layer*3 + which)
//  z 9..10: cw_nt[z-9] = (bf16)conv_w[z-9] (straight convert, layers 0..1)
// ---------------------------------------------------------------------------
__global__ __launch_bounds__(256) void wconv_kernel(
    const float* __restrict__ f0_w, const float* __restrict__ f1_w,
    const float* __restrict__ conv_w, __bf16* __restrict__ wt_all,
    __bf16* __restrict__ cw_nt)
{
    const int z = blockIdx.z;
    const int kx = blockIdx.x * 32, nx = blockIdx.y * 32;
    const int tx = threadIdx.x, ty = threadIdx.y;

    if (z < 9) {
        const int layer = z / 3, which = z % 3;
        const float* W = ((which == 0) ? f0_w : (which == 1) ? f1_w : conv_w)
                         + (size_t)layer * WSZ;
        __bf16* T = wt_all + (size_t)z * WSZ;

        __shared__ float tile[32][33];
        for (int i = ty; i < 32; i += 8)
            tile[i][tx] = W[(size_t)(kx + i) * HIDDEN + nx + tx];
        __syncthreads();
        for (int i = ty; i < 32; i += 8)
            T[(size_t)(nx + i) * HIDDEN + kx + tx] = (__bf16)tile[tx][i];
    } else {
        const int layer = z - 9;
        const float* W = conv_w + (size_t)layer * WSZ;
        __bf16* T = cw_nt + (size_t)layer * WSZ;
        for (int i = ty; i < 32; i += 8)
            T[(size_t)(kx + i) * HIDDEN + nx + tx] =
                (__bf16)W[(size_t)(kx + i) * HIDDEN + nx + tx];
    }
}

// ---------------------------------------------------------------------------
// Bias products: q[z][n] = sum_k conv_b[l][k] * W[k][n], k-split 4 ways
// (grid 16; qv pre-zeroed; fp32 atomics).
// z = 0..3: (l=0,F0_1),(l=0,F1_1),(l=1,F0_2),(l=1,F1_2).
// ---------------------------------------------------------------------------
__global__ __launch_bounds__(256) void qprod_kernel(
    const float* __restrict__ conv_b, const float* __restrict__ f0_w,
    const float* __restrict__ f1_w, float* __restrict__ q)
{
    const int z = blockIdx.x >> 2;
    const int kq = blockIdx.x & 3;
    const int l = z >> 1, branch = z & 1;
    const float* cb = conv_b + (size_t)l * HIDDEN;
    const float* W  = (branch ? f1_w : f0_w) + (size_t)(l + 1) * WSZ;
    const int n = threadIdx.x;

    float s = 0.f;
    #pragma unroll 4
    for (int k = kq * 64; k < kq * 64 + 64; ++k)
        s += cb[k] * W[(size_t)k * HIDDEN + n];
    atomicAdd(&q[(size_t)z * HIDDEN + n], s);
}

// ---------------------------------------------------------------------------
// CSR build: histogram -> 2-level exclusive scan (in-place offs) -> fill
// ---------------------------------------------------------------------------
__global__ __launch_bounds__(256) void hist_kernel(
    const int* __restrict__ dst, int* __restrict__ counts)
{
    int e = blockIdx.x * 256 + threadIdx.x;
    if (e < N_EDGES) atomicAdd(&counts[dst[e]], 1);
}

__device__ __forceinline__ int block_incl_scan(int v, int* s, int t)
{
    s[t] = v; __syncthreads();
    #pragma unroll
    for (int off = 1; off < 256; off <<= 1) {
        int add = (t >= off) ? s[t - off] : 0;
        __syncthreads();
        s[t] += add;
        __syncthreads();
    }
    return s[t];
}

__global__ __launch_bounds__(256) void scan1_kernel(
    const int* __restrict__ counts, int* __restrict__ offs, int* __restrict__ bsum)
{
    __shared__ int s[256];
    const int t = threadIdx.x;
    const int i = blockIdx.x * 256 + t;
    const int v = counts[i];
    int incl = block_incl_scan(v, s, t);
    offs[i] = incl - v;
    if (t == 255) bsum[blockIdx.x] = incl;
}

__global__ __launch_bounds__(256) void scan2_kernel(
    const int* __restrict__ bsum, int* __restrict__ bbase)
{
    __shared__ int s[256];
    const int t = threadIdx.x;
    const int v = (t < SCAN_BLOCKS) ? bsum[t] : 0;
    int incl = block_incl_scan(v, s, t);
    bbase[t] = incl - v;
}

__global__ __launch_bounds__(256) void scan3_kernel(
    int* __restrict__ offs, const int* __restrict__ bbase, int* __restrict__ cursor)
{
    const int i = blockIdx.x * 256 + threadIdx.x;
    const int o = offs[i] + bbase[blockIdx.x];
    offs[i] = o;
    cursor[i] = o;
}

__global__ __launch_bounds__(256) void fill_kernel(
    const int* __restrict__ src, const int* __restrict__ dst,
    int* __restrict__ cursor, int* __restrict__ src_sorted)
{
    int e = blockIdx.x * 256 + threadIdx.x;
    if (e < N_EDGES) {
        int p = atomicAdd(&cursor[dst[e]], 1);
        src_sorted[p] = src[e];
    }
}

// ---------------------------------------------------------------------------
// Pull-mode bf16 segment sum v5 — half-wave-per-dst + software pipelining:
//  - each HALF-WAVE (32 lanes x 16 B = full 512 B row) owns one dst node.
//  - groups of 4 edges; NEXT group's 4 row-loads are issued BEFORE the
//    current group's accumulate, keeping 4-8 loads in flight through the
//    ~128-cyc accumulate (R10 drained to 0 in flight during accumulation).
//  - all __shfl sources lie within the reader's own half -> divergence-safe
//    even when the two halves' trip counts differ (R5 lesson).
// COMPACT: node list from nodelist[], output compact rows.
// ---------------------------------------------------------------------------
template <bool COMPACT>
__global__ __launch_bounds__(256) void seg_sum5_kernel(
    const __bf16* __restrict__ x0,
    const int* __restrict__ srcs,
    const int* __restrict__ offs,
    const int* __restrict__ nodelist,
    __bf16* __restrict__ out)
{
    const int t    = threadIdx.x;
    const int wave = t >> 6;
    const int lane = t & 63;
    const int half = lane >> 5;
    const int li   = lane & 31;
    const int row  = blockIdx.x * 8 + wave * 2 + half;
    const int d    = COMPACT ? nodelist[row] : row;
    const int beg  = offs[d];
    const int deg  = offs[d + 1] - beg;
    const int hb   = half * 32;            // shfl base lane of this half

    const __bf16* xs = x0 + li * 8;        // this lane's 16-B column piece

    float a[8];
    #pragma unroll
    for (int k = 0; k < 8; ++k) a[k] = 0.f;

    for (int base = 0; base < deg; base += 32) {
        const int n = min(32, deg - base);             // half-uniform
        int vs = 0;
        if (li < n) vs = srcs[beg + base + li];
        const int nv = n & ~3;                         // full 4-groups

        bf16x8 c0, c1, c2, c3;
        if (nv) {   // prologue: issue group 0
            const int s0 = __shfl(vs, hb + 0), s1 = __shfl(vs, hb + 1);
            const int s2 = __shfl(vs, hb + 2), s3 = __shfl(vs, hb + 3);
            c0 = *(const bf16x8*)(xs + (size_t)s0 * HIDDEN);
            c1 = *(const bf16x8*)(xs + (size_t)s1 * HIDDEN);
            c2 = *(const bf16x8*)(xs + (size_t)s2 * HIDDEN);
            c3 = *(const bf16x8*)(xs + (size_t)s3 * HIDDEN);
        }
        for (int j = 4; j + 4 <= nv; j += 4) {
            // issue next group's loads before touching current data
            const int s0 = __shfl(vs, hb + j + 0), s1 = __shfl(vs, hb + j + 1);
            const int s2 = __shfl(vs, hb + j + 2), s3 = __shfl(vs, hb + j + 3);
            const bf16x8 n0 = *(const bf16x8*)(xs + (size_t)s0 * HIDDEN);
            const bf16x8 n1 = *(const bf16x8*)(xs + (size_t)s1 * HIDDEN);
            const bf16x8 n2 = *(const bf16x8*)(xs + (size_t)s2 * HIDDEN);
            const bf16x8 n3 = *(const bf16x8*)(xs + (size_t)s3 * HIDDEN);
            #pragma unroll
            for (int k = 0; k < 8; ++k)
                a[k] += (float)c0[k] + (float)c1[k] + (float)c2[k] + (float)c3[k];
            c0 = n0; c1 = n1; c2 = n2; c3 = n3;
        }
        if (nv) {   // epilogue: accumulate last full group
            #pragma unroll
            for (int k = 0; k < 8; ++k)
                a[k] += (float)c0[k] + (float)c1[k] + (float)c2[k] + (float)c3[k];
        }
        for (int j = nv; j < n; ++j) {     // scalar tail (<4 edges)
            const int s = __shfl(vs, hb + j);
            const bf16x8 v = *(const bf16x8*)(xs + (size_t)s * HIDDEN);
            #pragma unroll
            for (int k = 0; k < 8; ++k) a[k] += (float)v[k];
        }
    }

    bf16x8 o;
    #pragma unroll
    for (int k = 0; k < 8; ++k) o[k] = (__bf16)a[k];
    *(bf16x8*)(out + (size_t)row * HIDDEN + li * 8) = o;
}

extern "C" void kernel_launch(void* const* d_in, const int* in_sizes, int n_in,
                              void* d_out, int out_size, void* d_ws, size_t ws_size,
                              hipStream_t stream)
{
    const float* x       = (const float*)d_in[0];
    const float* f0_w    = (const float*)d_in[1];
    const float* f0_b    = (const float*)d_in[2];
    const float* f1_w    = (const float*)d_in[3];
    const float* f1_b    = (const float*)d_in[4];
    const float* conv_w  = (const float*)d_in[5];
    const float* conv_b  = (const float*)d_in[6];
    const int*   edge_src = (const int*)d_in[7];
    const int*   edge_dst = (const int*)d_in[8];
    const int*   pos      = (const int*)d_in[9];
    float* out = (float*)d_out;

    const size_t buf = (size_t)N_NODES * HIDDEN;   // 12.8M elems

    char* p = (char*)d_ws;
    __bf16* bufA   = (__bf16*)p; p += buf * 2;      // 25.6 MB
    __bf16* bufB   = (__bf16*)p; p += buf * 2;      // 25.6 MB
    __bf16* s_lbl  = (__bf16*)p; p += (size_t)N_LABEL * HIDDEN * 2;  // 4 MB
    __bf16* wt_all = (__bf16*)p; p += (size_t)9 * WSZ * 2;  // 9 transposed W
    __bf16* prod   = (__bf16*)p; p += (size_t)4 * WSZ * 2;  // 4 products
    __bf16* cw_nt  = (__bf16*)p; p += (size_t)2 * WSZ * 2;  // Cw layers 0,1 (no T)
    float*  qv     = (float*)p;  p += (size_t)4 * HIDDEN * 4;
    int* counts     = (int*)p;  p += NPAD * 4;     // reused as cursor
    int* offs       = (int*)p;  p += NPAD * 4;
    int* bsum       = (int*)p;  p += 256 * 4;
    int* bbase      = (int*)p;  p += 256 * 4;
    int* src_sorted = (int*)p;  p += (size_t)N_EDGES * 4;
    int* cursor = counts;       // counts dead after scan1

    const int edge_blocks = (N_EDGES + 255) / 256;   // 3125

    // ---- CSR build (edges layer-invariant) ----
    hipMemsetAsync(counts, 0, NPAD * sizeof(int), stream);
    hist_kernel<<<edge_blocks, 256, 0, stream>>>(edge_dst, counts);
    scan1_kernel<<<SCAN_BLOCKS, 256, 0, stream>>>(counts, offs, bsum);
    scan2_kernel<<<1, 256, 0, stream>>>(bsum, bbase);
    scan3_kernel<<<SCAN_BLOCKS, 256, 0, stream>>>(offs, bbase, cursor);
    fill_kernel<<<edge_blocks, 256, 0, stream>>>(edge_src, edge_dst, cursor, src_sorted);

    // ---- weights: transpose+bf16 (9) + straight Cw (2) in one launch ----
    wconv_kernel<<<dim3(8, 8, 11), dim3(32, 8), 0, stream>>>(
        f0_w, f1_w, conv_w, wt_all, cw_nt);
    hipMemsetAsync(qv, 0, 4 * HIDDEN * sizeof(float), stream);
    qprod_kernel<<<16, 256, 0, stream>>>(conv_b, f0_w, f1_w, qv);

    // all 4 products prod_t[z] = (Cw_l · F_{l+1})^T in ONE batched launch
    mfma_gemm<false, false, false, false, false, true, true, false>
        <<<dim3(2, 2, 4), 256, 0, stream>>>(
        wt_all, cw_nt, nullptr, nullptr, prod, nullptr, nullptr, HIDDEN);

    const dim3 gemm_grid(391, 2);    // ceil(50000/128) x (256/128)
    const dim3 lbl_grid(64, 2);      // 8192/128 x 2

    __bf16* cur = bufA;              // S buffer (layer-0 GEMMs read x fp32)
    __bf16* tmp = bufB;

    for (int l = 0; l < N_LAYERS; ++l) {
        const float* B0 = f0_b + (size_t)l * HIDDEN;
        const float* B1 = f1_b + (size_t)l * HIDDEN;

        if (l == 0) {
            // x0 = x @ F0_0 + b0   (A fp32, conversion fused into staging)
            mfma_gemm<false, false, false, false, true, true, false, true>
                <<<gemm_grid, 256, 0, stream>>>(
                x, wt_all + 0 * WSZ, nullptr, B0, tmp, nullptr, nullptr, N_NODES);
            // x0[idx] = x[idx] @ F1_0 + b1
            mfma_gemm<true, true, false, false, true, true, false, true>
                <<<lbl_grid, 256, 0, stream>>>(
                x, wt_all + 1 * WSZ, nullptr, B1, tmp, pos, nullptr, N_LABEL);
        } else {
            // x0 = S @ (Cw_{l-1}·F0_l) + deg*q0 + b0   (conv folded in)
            const int z0 = (l - 1) * 2;
            mfma_gemm<false, false, true, false, true, true, false, false>
                <<<gemm_grid, 256, 0, stream>>>(
                cur, prod + (size_t)z0 * WSZ, qv + (size_t)z0 * HIDDEN, B0,
                tmp, nullptr, offs, N_NODES);
            mfma_gemm<true, true, true, false, true, true, false, false>
                <<<lbl_grid, 256, 0, stream>>>(
                cur, prod + (size_t)(z0 + 1) * WSZ, qv + (size_t)(z0 + 1) * HIDDEN,
                B1, tmp, pos, offs, N_LABEL);
        }

        if (l < N_LAYERS - 1) {
            // S = segment_sum(x0[src]) at ALL nodes (tmp -> cur)
            seg_sum5_kernel<false><<<N_NODES / 8, 256, 0, stream>>>(
                tmp, src_sorted, offs, nullptr, cur);
        } else {
            // S only at labeled dst nodes (tmp -> s_lbl, compact pos order)
            seg_sum5_kernel<true><<<N_LABEL / 8, 256, 0, stream>>>(
                tmp, src_sorted, offs, pos, s_lbl);
            // out[i] = S_lbl[i] @ Cw_2 + deg[pos[i]]*cb_2  -> d_out (fp32)
            mfma_gemm<false, false, true, true, false, false, false, false>
                <<<lbl_grid, 256, 0, stream>>>(
                s_lbl, wt_all + (size_t)(2 * 3 + 2) * WSZ,
                conv_b + (size_t)2 * HIDDEN, nullptr, out, pos, offs, N_LABEL);
        }
    }
}

// Round 12
// 437.137 us; speedup vs baseline: 1.4279x; 1.0019x over previous
//
#include <hip/hip_runtime.h>
#include <hip/hip_bf16.h>

#define N_NODES 50000
#define N_EDGES 800000
#define HIDDEN  256
#define N_LAYERS 3
#define N_PAIRS 4096
#define N_LABEL 8192            // 2*N_PAIRS labeled rows
#define NPAD    50176           // 196*256, padded node count for the scan
#define SCAN_BLOCKS (NPAD / 256) // 196
#define WSZ (HIDDEN * HIDDEN)    // 65536 elems per weight matrix

typedef __bf16 bf16x8 __attribute__((ext_vector_type(8)));
typedef __bf16 bf16x4 __attribute__((ext_vector_type(4)));
typedef float  f32x4  __attribute__((ext_vector_type(4)));

__device__ __forceinline__ void load_lds16(const void* g, void* l) {
    __builtin_amdgcn_global_load_lds(
        (const __attribute__((address_space(1))) void*)g,
        (__attribute__((address_space(3))) void*)l, 16, 0, 0);
}

// ---------------------------------------------------------------------------
// MFMA GEMM: C = A @ Wt^T (+ deg*biasD) (+ biasC).  Wt bf16 [n][k].
// 64x128 tile (R12: halved TM doubles resident blocks -> hides the skinny-K
// staging latency that capped the 128x128 version at ~35 us), BK=32,
// 4 waves stacked in m; each wave = 1x8 16x16x32 fragments (32 acc VGPRs).
//   GATHER_A   : A-rows indirect through idx
//   SCATTER_C  : C-rows indirect through idx (dup-idx identical: benign)
//   DEG_BIAS   : add deg[node]*biasD[col], deg = offs[node+1]-offs[node]
//   DEG_VIA_IDX: node for deg lookup is idx[row] (A-rows sequential/compact)
//   HAS_BIAS   : add biasC[col]
//   OUT_BF16   : output dtype
//   PROD_BATCH : blockIdx.z = z in 0..3 selects the 4 weight-product GEMMs
//   A_FP32     : A is fp32; stage via f32 loads + in-reg bf16 convert +
//                ds_write (fuses the x->bf16 conversion into layer-0 GEMMs)
// ---------------------------------------------------------------------------
template <bool GATHER_A, bool SCATTER_C, bool DEG_BIAS, bool DEG_VIA_IDX,
          bool HAS_BIAS, bool OUT_BF16, bool PROD_BATCH, bool A_FP32>
__global__ __launch_bounds__(256) void mfma_gemm(
    const void* __restrict__ A_in,     // bf16 or fp32 per A_FP32
    const __bf16* __restrict__ Wt_in,  // (256,256) bf16, Wt[n][k]
    const float* __restrict__ biasD,   // deg-scaled bias (or null)
    const float* __restrict__ biasC,   // plain bias (or null)
    void* __restrict__ Cout_in,
    const int* __restrict__ idx,
    const int* __restrict__ offs,
    int M)
{
    const __bf16* A  = (const __bf16*)A_in;
    const float*  A32 = (const float*)A_in;
    const __bf16* Wt = Wt_in;
    void* Cout = Cout_in;
    if constexpr (PROD_BATCH) {
        const int z = blockIdx.z;
        A    = (const __bf16*)A_in + (size_t)(3 * (1 + (z >> 1)) + (z & 1)) * WSZ;
        Wt   = Wt_in + (size_t)(z >> 1) * WSZ;
        Cout = (void*)((__bf16*)Cout_in + (size_t)z * WSZ);
    }

    __shared__ __bf16 As[64 * 32];    // [row][k] 4 KB
    __shared__ __bf16 Bs[128 * 32];   // [n][k]   8 KB
    __shared__ int s_idx[64];

    const int t    = threadIdx.x;
    const int lane = t & 63;
    const int wave = t >> 6;
    const int m0   = blockIdx.x * 64;
    const int n0   = blockIdx.y * 128;

    if constexpr (GATHER_A || SCATTER_C || DEG_VIA_IDX) {
        if (t < 64) s_idx[t] = idx[m0 + t];
        __syncthreads();
    }

    // A staging: chunk c = t (1/thread); row = c>>2, col8 = (c&3)*8
    // B staging: chunks c = r*256 + t (2/thread)
    // LDS dest offset = c*16 bytes (wave-uniform base + lane*16: m104-safe)
    const int arow  = t >> 2;
    const int acol8 = (t & 3) * 8;
    int anode;
    if constexpr (GATHER_A) {
        anode = s_idx[arow];
    } else {
        const int rg = m0 + arow;
        anode = (rg < M) ? rg : (M - 1);   // clamp; stores guarded below
    }
    const __bf16* aptr   = A   + (size_t)anode * HIDDEN + acol8;
    const float*  aptr32 = A32 + (size_t)anode * HIDDEN + acol8;

    const __bf16* bptr[2];
    #pragma unroll
    for (int r = 0; r < 2; ++r) {
        const int c = r * 256 + t;
        bptr[r] = Wt + (size_t)(n0 + (c >> 2)) * HIDDEN + (c & 3) * 8;
    }

    f32x4 acc[8];
    #pragma unroll
    for (int i = 0; i < 8; ++i) acc[i] = (f32x4){0.f, 0.f, 0.f, 0.f};

    const int wm   = wave * 16;       // waves stacked in m
    const int fm   = lane & 15;
    const int quad = lane >> 4;

    for (int k0 = 0; k0 < HIDDEN; k0 += 32) {
        __syncthreads();
        if constexpr (A_FP32) {
            const float* ap = aptr32 + k0;
            const float4 u0 = *(const float4*)(ap);
            const float4 u1 = *(const float4*)(ap + 4);
            bf16x8 w = {(__bf16)u0.x, (__bf16)u0.y, (__bf16)u0.z, (__bf16)u0.w,
                        (__bf16)u1.x, (__bf16)u1.y, (__bf16)u1.z, (__bf16)u1.w};
            *(bf16x8*)(As + (size_t)t * 8) = w;
        } else {
            load_lds16(aptr + k0, (void*)(As + (size_t)t * 8));
        }
        #pragma unroll
        for (int r = 0; r < 2; ++r)
            load_lds16(bptr[r] + k0, (void*)(Bs + (size_t)(r * 256 + t) * 8));
        __syncthreads();   // drains vmcnt+lgkmcnt: staged data visible

        const bf16x8 af = *(const bf16x8*)(As + (wm + fm) * 32 + quad * 8);
        bf16x8 bfr[8];
        #pragma unroll
        for (int nt = 0; nt < 8; ++nt)
            bfr[nt] = *(const bf16x8*)(Bs + (nt * 16 + fm) * 32 + quad * 8);

        #pragma unroll
        for (int nt = 0; nt < 8; ++nt)
            acc[nt] = __builtin_amdgcn_mfma_f32_16x16x32_bf16(
                af, bfr[nt], acc[nt], 0, 0, 0);
    }

    // epilogue: C/D layout col=lane&15, row=quad*4+reg (m89/m91-verified)
    float bd[8], bc[8];
    #pragma unroll
    for (int nt = 0; nt < 8; ++nt) {
        const int col = n0 + nt * 16 + fm;
        bd[nt] = DEG_BIAS ? biasD[col] : 0.f;
        bc[nt] = HAS_BIAS ? biasC[col] : 0.f;
    }

    #pragma unroll
    for (int rg = 0; rg < 4; ++rg) {
        const int rloc = wm + quad * 4 + rg;
        int orow;
        if constexpr (SCATTER_C) {
            orow = s_idx[rloc];
        } else {
            orow = m0 + rloc;
            if (orow >= M) continue;
        }
        float bscale = 0.f;
        if constexpr (DEG_BIAS) {
            int dnode;
            if constexpr (DEG_VIA_IDX || GATHER_A) dnode = s_idx[rloc];
            else                                   dnode = m0 + rloc;
            bscale = (float)(offs[dnode + 1] - offs[dnode]);
        }
        #pragma unroll
        for (int nt = 0; nt < 8; ++nt) {
            const int col = n0 + nt * 16 + fm;
            float v = acc[nt][rg];
            if constexpr (DEG_BIAS) v += bscale * bd[nt];
            if constexpr (HAS_BIAS) v += bc[nt];
            if constexpr (OUT_BF16)
                ((__bf16*)Cout)[(size_t)orow * HIDDEN + col] = (__bf16)v;
            else
                ((float*)Cout)[(size_t)orow * HIDDEN + col] = v;
        }
    }
}

// ---------------------------------------------------------------------------
// Weight prep, 11 z-slices in ONE launch:
//  z 0..8 : T[z][n][k] = (bf16)W_z[k][n]   (transpose; z = layer*3 + which)
//  z 9..10: cw_nt[z-9] = (bf16)conv_w[z-9] (straight convert, layers 0..1)
// ---------------------------------------------------------------------------
__global__ __launch_bounds__(256) void wconv_kernel(
    const float* __restrict__ f0_w, const float* __restrict__ f1_w,
    const float* __restrict__ conv_w, __bf16* __restrict__ wt_all,
    __bf16* __restrict__ cw_nt)
{
    const int z = blockIdx.z;
    const int kx = blockIdx.x * 32, nx = blockIdx.y * 32;
    const int tx = threadIdx.x, ty = threadIdx.y;

    if (z < 9) {
        const int layer = z / 3, which = z % 3;
        const float* W = ((which == 0) ? f0_w : (which == 1) ? f1_w : conv_w)
                         + (size_t)layer * WSZ;
        __bf16* T = wt_all + (size_t)z * WSZ;

        __shared__ float tile[32][33];
        for (int i = ty; i < 32; i += 8)
            tile[i][tx] = W[(size_t)(kx + i) * HIDDEN + nx + tx];
        __syncthreads();
        for (int i = ty; i < 32; i += 8)
            T[(size_t)(nx + i) * HIDDEN + kx + tx] = (__bf16)tile[tx][i];
    } else {
        const int layer = z - 9;
        const float* W = conv_w + (size_t)layer * WSZ;
        __bf16* T = cw_nt + (size_t)layer * WSZ;
        for (int i = ty; i < 32; i += 8)
            T[(size_t)(kx + i) * HIDDEN + nx + tx] =
                (__bf16)W[(size_t)(kx + i) * HIDDEN + nx + tx];
    }
}

// ---------------------------------------------------------------------------
// Bias products: q[z][n] = sum_k conv_b[l][k] * W[k][n].  One block per z,
// non-atomic direct write (drops the qv memset dispatch of R11).
// z = 0..3: (l=0,F0_1),(l=0,F1_1),(l=1,F0_2),(l=1,F1_2).
// ---------------------------------------------------------------------------
__global__ __launch_bounds__(256) void qprod_kernel(
    const float* __restrict__ conv_b, const float* __restrict__ f0_w,
    const float* __restrict__ f1_w, float* __restrict__ q)
{
    const int z = blockIdx.x;
    const int l = z >> 1, branch = z & 1;
    const float* cb = conv_b + (size_t)l * HIDDEN;
    const float* W  = (branch ? f1_w : f0_w) + (size_t)(l + 1) * WSZ;
    const int n = threadIdx.x;

    float s = 0.f;
    #pragma unroll 4
    for (int k = 0; k < HIDDEN; ++k)
        s += cb[k] * W[(size_t)k * HIDDEN + n];
    q[(size_t)z * HIDDEN + n] = s;
}

// ---------------------------------------------------------------------------
// CSR build: histogram -> 2-level exclusive scan (in-place offs) -> fill
// ---------------------------------------------------------------------------
__global__ __launch_bounds__(256) void hist_kernel(
    const int* __restrict__ dst, int* __restrict__ counts)
{
    int e = blockIdx.x * 256 + threadIdx.x;
    if (e < N_EDGES) atomicAdd(&counts[dst[e]], 1);
}

__device__ __forceinline__ int block_incl_scan(int v, int* s, int t)
{
    s[t] = v; __syncthreads();
    #pragma unroll
    for (int off = 1; off < 256; off <<= 1) {
        int add = (t >= off) ? s[t - off] : 0;
        __syncthreads();
        s[t] += add;
        __syncthreads();
    }
    return s[t];
}

__global__ __launch_bounds__(256) void scan1_kernel(
    const int* __restrict__ counts, int* __restrict__ offs, int* __restrict__ bsum)
{
    __shared__ int s[256];
    const int t = threadIdx.x;
    const int i = blockIdx.x * 256 + t;
    const int v = counts[i];
    int incl = block_incl_scan(v, s, t);
    offs[i] = incl - v;
    if (t == 255) bsum[blockIdx.x] = incl;
}

__global__ __launch_bounds__(256) void scan2_kernel(
    const int* __restrict__ bsum, int* __restrict__ bbase)
{
    __shared__ int s[256];
    const int t = threadIdx.x;
    const int v = (t < SCAN_BLOCKS) ? bsum[t] : 0;
    int incl = block_incl_scan(v, s, t);
    bbase[t] = incl - v;
}

__global__ __launch_bounds__(256) void scan3_kernel(
    int* __restrict__ offs, const int* __restrict__ bbase, int* __restrict__ cursor)
{
    const int i = blockIdx.x * 256 + threadIdx.x;
    const int o = offs[i] + bbase[blockIdx.x];
    offs[i] = o;
    cursor[i] = o;
}

__global__ __launch_bounds__(256) void fill_kernel(
    const int* __restrict__ src, const int* __restrict__ dst,
    int* __restrict__ cursor, int* __restrict__ src_sorted)
{
    int e = blockIdx.x * 256 + threadIdx.x;
    if (e < N_EDGES) {
        int p = atomicAdd(&cursor[dst[e]], 1);
        src_sorted[p] = src[e];
    }
}

// ---------------------------------------------------------------------------
// Pull-mode bf16 segment sum v5 — half-wave-per-dst + software pipelining.
// (R11-verified; at its structural random-gather ceiling ~56 us: 4 different
// structures all land 56-65 us, FETCH pinned at ~173 MB = 7x per-XCD L2 fill.)
// COMPACT: node list from nodelist[], output compact rows.
// ---------------------------------------------------------------------------
template <bool COMPACT>
__global__ __launch_bounds__(256) void seg_sum5_kernel(
    const __bf16* __restrict__ x0,
    const int* __restrict__ srcs,
    const int* __restrict__ offs,
    const int* __restrict__ nodelist,
    __bf16* __restrict__ out)
{
    const int t    = threadIdx.x;
    const int wave = t >> 6;
    const int lane = t & 63;
    const int half = lane >> 5;
    const int li   = lane & 31;
    const int row  = blockIdx.x * 8 + wave * 2 + half;
    const int d    = COMPACT ? nodelist[row] : row;
    const int beg  = offs[d];
    const int deg  = offs[d + 1] - beg;
    const int hb   = half * 32;            // shfl base lane of this half

    const __bf16* xs = x0 + li * 8;        // this lane's 16-B column piece

    float a[8];
    #pragma unroll
    for (int k = 0; k < 8; ++k) a[k] = 0.f;

    for (int base = 0; base < deg; base += 32) {
        const int n = min(32, deg - base);             // half-uniform
        int vs = 0;
        if (li < n) vs = srcs[beg + base + li];
        const int nv = n & ~3;                         // full 4-groups

        bf16x8 c0, c1, c2, c3;
        if (nv) {   // prologue: issue group 0
            const int s0 = __shfl(vs, hb + 0), s1 = __shfl(vs, hb + 1);
            const int s2 = __shfl(vs, hb + 2), s3 = __shfl(vs, hb + 3);
            c0 = *(const bf16x8*)(xs + (size_t)s0 * HIDDEN);
            c1 = *(const bf16x8*)(xs + (size_t)s1 * HIDDEN);
            c2 = *(const bf16x8*)(xs + (size_t)s2 * HIDDEN);
            c3 = *(const bf16x8*)(xs + (size_t)s3 * HIDDEN);
        }
        for (int j = 4; j + 4 <= nv; j += 4) {
            // issue next group's loads before touching current data
            const int s0 = __shfl(vs, hb + j + 0), s1 = __shfl(vs, hb + j + 1);
            const int s2 = __shfl(vs, hb + j + 2), s3 = __shfl(vs, hb + j + 3);
            const bf16x8 n0 = *(const bf16x8*)(xs + (size_t)s0 * HIDDEN);
            const bf16x8 n1 = *(const bf16x8*)(xs + (size_t)s1 * HIDDEN);
            const bf16x8 n2 = *(const bf16x8*)(xs + (size_t)s2 * HIDDEN);
            const bf16x8 n3 = *(const bf16x8*)(xs + (size_t)s3 * HIDDEN);
            #pragma unroll
            for (int k = 0; k < 8; ++k)
                a[k] += (float)c0[k] + (float)c1[k] + (float)c2[k] + (float)c3[k];
            c0 = n0; c1 = n1; c2 = n2; c3 = n3;
        }
        if (nv) {   // epilogue: accumulate last full group
            #pragma unroll
            for (int k = 0; k < 8; ++k)
                a[k] += (float)c0[k] + (float)c1[k] + (float)c2[k] + (float)c3[k];
        }
        for (int j = nv; j < n; ++j) {     // scalar tail (<4 edges)
            const int s = __shfl(vs, hb + j);
            const bf16x8 v = *(const bf16x8*)(xs + (size_t)s * HIDDEN);
            #pragma unroll
            for (int k = 0; k < 8; ++k) a[k] += (float)v[k];
        }
    }

    bf16x8 o;
    #pragma unroll
    for (int k = 0; k < 8; ++k) o[k] = (__bf16)a[k];
    *(bf16x8*)(out + (size_t)row * HIDDEN + li * 8) = o;
}

extern "C" void kernel_launch(void* const* d_in, const int* in_sizes, int n_in,
                              void* d_out, int out_size, void* d_ws, size_t ws_size,
                              hipStream_t stream)
{
    const float* x       = (const float*)d_in[0];
    const float* f0_w    = (const float*)d_in[1];
    const float* f0_b    = (const float*)d_in[2];
    const float* f1_w    = (const float*)d_in[3];
    const float* f1_b    = (const float*)d_in[4];
    const float* conv_w  = (const float*)d_in[5];
    const float* conv_b  = (const float*)d_in[6];
    const int*   edge_src = (const int*)d_in[7];
    const int*   edge_dst = (const int*)d_in[8];
    const int*   pos      = (const int*)d_in[9];
    float* out = (float*)d_out;

    const size_t buf = (size_t)N_NODES * HIDDEN;   // 12.8M elems

    char* p = (char*)d_ws;
    __bf16* bufA   = (__bf16*)p; p += buf * 2;      // 25.6 MB
    __bf16* bufB   = (__bf16*)p; p += buf * 2;      // 25.6 MB
    __bf16* s_lbl  = (__bf16*)p; p += (size_t)N_LABEL * HIDDEN * 2;  // 4 MB
    __bf16* wt_all = (__bf16*)p; p += (size_t)9 * WSZ * 2;  // 9 transposed W
    __bf16* prod   = (__bf16*)p; p += (size_t)4 * WSZ * 2;  // 4 products
    __bf16* cw_nt  = (__bf16*)p; p += (size_t)2 * WSZ * 2;  // Cw layers 0,1 (no T)
    float*  qv     = (float*)p;  p += (size_t)4 * HIDDEN * 4;
    int* counts     = (int*)p;  p += NPAD * 4;     // reused as cursor
    int* offs       = (int*)p;  p += NPAD * 4;
    int* bsum       = (int*)p;  p += 256 * 4;
    int* bbase      = (int*)p;  p += 256 * 4;
    int* src_sorted = (int*)p;  p += (size_t)N_EDGES * 4;
    int* cursor = counts;       // counts dead after scan1

    const int edge_blocks = (N_EDGES + 255) / 256;   // 3125

    // ---- CSR build (edges layer-invariant) ----
    hipMemsetAsync(counts, 0, NPAD * sizeof(int), stream);
    hist_kernel<<<edge_blocks, 256, 0, stream>>>(edge_dst, counts);
    scan1_kernel<<<SCAN_BLOCKS, 256, 0, stream>>>(counts, offs, bsum);
    scan2_kernel<<<1, 256, 0, stream>>>(bsum, bbase);
    scan3_kernel<<<SCAN_BLOCKS, 256, 0, stream>>>(offs, bbase, cursor);
    fill_kernel<<<edge_blocks, 256, 0, stream>>>(edge_src, edge_dst, cursor, src_sorted);

    // ---- weights: transpose+bf16 (9) + straight Cw (2) in one launch ----
    wconv_kernel<<<dim3(8, 8, 11), dim3(32, 8), 0, stream>>>(
        f0_w, f1_w, conv_w, wt_all, cw_nt);
    qprod_kernel<<<4, 256, 0, stream>>>(conv_b, f0_w, f1_w, qv);

    // all 4 products prod_t[z] = (Cw_l · F_{l+1})^T in ONE batched launch
    mfma_gemm<false, false, false, false, false, true, true, false>
        <<<dim3(4, 2, 4), 256, 0, stream>>>(
        wt_all, cw_nt, nullptr, nullptr, prod, nullptr, nullptr, HIDDEN);

    const dim3 gemm_grid(782, 2);    // ceil(50000/64) x (256/128)
    const dim3 lbl_grid(128, 2);     // 8192/64 x 2

    __bf16* cur = bufA;              // S buffer (layer-0 GEMMs read x fp32)
    __bf16* tmp = bufB;

    for (int l = 0; l < N_LAYERS; ++l) {
        const float* B0 = f0_b + (size_t)l * HIDDEN;
        const float* B1 = f1_b + (size_t)l * HIDDEN;

        if (l == 0) {
            // x0 = x @ F0_0 + b0   (A fp32, conversion fused into staging)
            mfma_gemm<false, false, false, false, true, true, false, true>
                <<<gemm_grid, 256, 0, stream>>>(
                x, wt_all + 0 * WSZ, nullptr, B0, tmp, nullptr, nullptr, N_NODES);
            // x0[idx] = x[idx] @ F1_0 + b1
            mfma_gemm<true, true, false, false, true, true, false, true>
                <<<lbl_grid, 256, 0, stream>>>(
                x, wt_all + 1 * WSZ, nullptr, B1, tmp, pos, nullptr, N_LABEL);
        } else {
            // x0 = S @ (Cw_{l-1}·F0_l) + deg*q0 + b0   (conv folded in)
            const int z0 = (l - 1) * 2;
            mfma_gemm<false, false, true, false, true, true, false, false>
                <<<gemm_grid, 256, 0, stream>>>(
                cur, prod + (size_t)z0 * WSZ, qv + (size_t)z0 * HIDDEN, B0,
                tmp, nullptr, offs, N_NODES);
            mfma_gemm<true, true, true, false, true, true, false, false>
                <<<lbl_grid, 256, 0, stream>>>(
                cur, prod + (size_t)(z0 + 1) * WSZ, qv + (size_t)(z0 + 1) * HIDDEN,
                B1, tmp, pos, offs, N_LABEL);
        }

        if (l < N_LAYERS - 1) {
            // S = segment_sum(x0[src]) at ALL nodes (tmp -> cur)
            seg_sum5_kernel<false><<<N_NODES / 8, 256, 0, stream>>>(
                tmp, src_sorted, offs, nullptr, cur);
        } else {
            // S only at labeled dst nodes (tmp -> s_lbl, compact pos order)
            seg_sum5_kernel<true><<<N_LABEL / 8, 256, 0, stream>>>(
                tmp, src_sorted, offs, pos, s_lbl);
            // out[i] = S_lbl[i] @ Cw_2 + deg[pos[i]]*cb_2  -> d_out (fp32)
            mfma_gemm<false, false, true, true, false, false, false, false>
                <<<lbl_grid, 256, 0, stream>>>(
                s_lbl, wt_all + (size_t)(2 * 3 + 2) * WSZ,
                conv_b + (size_t)2 * HIDDEN, nullptr, out, pos, offs, N_LABEL);
        }
    }
}

// Round 14
// 417.684 us; speedup vs baseline: 1.4944x; 1.0466x over previous
//
#include <hip/hip_runtime.h>
#include <hip/hip_bf16.h>

#define N_NODES 50000
#define N_EDGES 800000
#define HIDDEN  256
#define N_LAYERS 3
#define N_PAIRS 4096
#define N_LABEL 8192            // 2*N_PAIRS labeled rows
#define NPAD    50176           // 196*256, padded node count for the scan
#define SCAN_BLOCKS (NPAD / 256) // 196
#define WSZ (HIDDEN * HIDDEN)    // 65536 elems per weight matrix

typedef __bf16 bf16x8 __attribute__((ext_vector_type(8)));
typedef __bf16 bf16x4 __attribute__((ext_vector_type(4)));
typedef float  f32x4  __attribute__((ext_vector_type(4)));

__device__ __forceinline__ void load_lds16(const void* g, void* l) {
    __builtin_amdgcn_global_load_lds(
        (const __attribute__((address_space(1))) void*)g,
        (__attribute__((address_space(3))) void*)l, 16, 0, 0);
}

// ---------------------------------------------------------------------------
// FUSED layer GEMM (R13): one launch does BOTH node linears of a layer.
//   blockIdx.z==0 : x0[r] = A[r]@Wt0^T (+deg*bD0) + bC0 for all r, but
//                   stores SUPPRESSED on labeled rows (flags[r]!=0)
//   blockIdx.z==1 : x0[idx[r]] = A[idx[r]]@Wt1^T (+deg*bD1) + bC1
//                   (only blockIdx.x < N_LABEL/64 active)
// Writes are disjoint by construction -> race-free in a single launch.
// 64x128 tile, BK=32, 4 waves stacked in m, 1x8 frags/wave.
//   DEG_BIAS: add deg[orow]*bD[col] (orow IS the node id in both roles)
//   A_FP32  : A fp32, converted in-register during staging (layer 0)
// ---------------------------------------------------------------------------
template <bool DEG_BIAS, bool A_FP32>
__global__ __launch_bounds__(256) void mfma_gemm_fused(
    const void* __restrict__ A_in,
    const __bf16* __restrict__ Wt0, const __bf16* __restrict__ Wt1,
    const float* __restrict__ bD0, const float* __restrict__ bD1,
    const float* __restrict__ bC0, const float* __restrict__ bC1,
    __bf16* __restrict__ Cout,
    const int* __restrict__ idx,     // pos (labeled rows)
    const int* __restrict__ offs,
    const int* __restrict__ flags,   // 1 = labeled row
    int M)
{
    const int role = blockIdx.z;
    if (role == 1 && blockIdx.x >= N_LABEL / 64) return;

    const __bf16* A   = (const __bf16*)A_in;
    const float*  A32 = (const float*)A_in;
    const __bf16* Wt  = role ? Wt1 : Wt0;
    const float*  bD  = role ? bD1 : bD0;
    const float*  bC  = role ? bC1 : bC0;

    __shared__ __bf16 As[64 * 32];    // 4 KB
    __shared__ __bf16 Bs[128 * 32];   // 8 KB
    __shared__ int s_idx[64];

    const int t    = threadIdx.x;
    const int lane = t & 63;
    const int wave = t >> 6;
    const int m0   = blockIdx.x * 64;
    const int n0   = blockIdx.y * 128;

    if (role == 1) {
        if (t < 64) s_idx[t] = idx[m0 + t];
        __syncthreads();
    }

    // A staging: chunk t; row=t>>2, col8=(t&3)*8. B: chunks r*256+t.
    // LDS dest = chunk*16 B (wave-uniform base + lane*16: m104-safe)
    const int arow  = t >> 2;
    const int acol8 = (t & 3) * 8;
    int anode;
    if (role == 1) {
        anode = s_idx[arow];
    } else {
        const int rg = m0 + arow;
        anode = (rg < M) ? rg : (M - 1);   // clamp; stores guarded below
    }
    const __bf16* aptr   = A   + (size_t)anode * HIDDEN + acol8;
    const float*  aptr32 = A32 + (size_t)anode * HIDDEN + acol8;

    const __bf16* bptr[2];
    #pragma unroll
    for (int r = 0; r < 2; ++r) {
        const int c = r * 256 + t;
        bptr[r] = Wt + (size_t)(n0 + (c >> 2)) * HIDDEN + (c & 3) * 8;
    }

    f32x4 acc[8];
    #pragma unroll
    for (int i = 0; i < 8; ++i) acc[i] = (f32x4){0.f, 0.f, 0.f, 0.f};

    const int wm   = wave * 16;
    const int fm   = lane & 15;
    const int quad = lane >> 4;

    for (int k0 = 0; k0 < HIDDEN; k0 += 32) {
        __syncthreads();
        if constexpr (A_FP32) {
            const float* ap = aptr32 + k0;
            const float4 u0 = *(const float4*)(ap);
            const float4 u1 = *(const float4*)(ap + 4);
            bf16x8 w = {(__bf16)u0.x, (__bf16)u0.y, (__bf16)u0.z, (__bf16)u0.w,
                        (__bf16)u1.x, (__bf16)u1.y, (__bf16)u1.z, (__bf16)u1.w};
            *(bf16x8*)(As + (size_t)t * 8) = w;
        } else {
            load_lds16(aptr + k0, (void*)(As + (size_t)t * 8));
        }
        #pragma unroll
        for (int r = 0; r < 2; ++r)
            load_lds16(bptr[r] + k0, (void*)(Bs + (size_t)(r * 256 + t) * 8));
        __syncthreads();

        const bf16x8 af = *(const bf16x8*)(As + (wm + fm) * 32 + quad * 8);
        bf16x8 bfr[8];
        #pragma unroll
        for (int nt = 0; nt < 8; ++nt)
            bfr[nt] = *(const bf16x8*)(Bs + (nt * 16 + fm) * 32 + quad * 8);

        #pragma unroll
        for (int nt = 0; nt < 8; ++nt)
            acc[nt] = __builtin_amdgcn_mfma_f32_16x16x32_bf16(
                af, bfr[nt], acc[nt], 0, 0, 0);
    }

    // epilogue: C/D layout col=lane&15, row=quad*4+reg (m89/m91-verified)
    float bd[8], bc[8];
    #pragma unroll
    for (int nt = 0; nt < 8; ++nt) {
        const int col = n0 + nt * 16 + fm;
        bd[nt] = DEG_BIAS ? bD[col] : 0.f;
        bc[nt] = bC[col];
    }

    #pragma unroll
    for (int rg = 0; rg < 4; ++rg) {
        const int rloc = wm + quad * 4 + rg;
        int orow;
        if (role == 1) {
            orow = s_idx[rloc];
        } else {
            orow = m0 + rloc;
            if (orow >= M) continue;
            if (flags[orow]) continue;     // labeled: z=1 writes this row
        }
        float bscale = 0.f;
        if constexpr (DEG_BIAS)
            bscale = (float)(offs[orow + 1] - offs[orow]);
        #pragma unroll
        for (int nt = 0; nt < 8; ++nt) {
            const int col = n0 + nt * 16 + fm;
            float v = acc[nt][rg];
            if constexpr (DEG_BIAS) v += bscale * bd[nt];
            v += bc[nt];
            Cout[(size_t)orow * HIDDEN + col] = (__bf16)v;
        }
    }
}

// ---------------------------------------------------------------------------
// Plain MFMA GEMM (product batch + final out GEMM).  64x128 tile.
//   GATHER_A   : A-rows gathered via idx (A indexed by node id)
//   DEG_VIA_IDX: A sequential/compact but deg looked up via idx[rloc]
//                (R13 bug fix: out GEMM reads compact s_lbl rows, NOT
//                s_lbl[pos[i]] — GATHER_A here was the NaN OOB read)
// ---------------------------------------------------------------------------
template <bool GATHER_A, bool DEG_BIAS, bool DEG_VIA_IDX, bool OUT_BF16, bool PROD_BATCH>
__global__ __launch_bounds__(256) void mfma_gemm(
    const __bf16* __restrict__ A_in,
    const __bf16* __restrict__ Wt_in,
    const float* __restrict__ biasD,
    void* __restrict__ Cout_in,
    const int* __restrict__ idx,
    const int* __restrict__ offs,
    int M)
{
    const __bf16* A  = A_in;
    const __bf16* Wt = Wt_in;
    void* Cout = Cout_in;
    if constexpr (PROD_BATCH) {
        const int z = blockIdx.z;
        A    = A_in  + (size_t)(3 * (1 + (z >> 1)) + (z & 1)) * WSZ;
        Wt   = Wt_in + (size_t)(z >> 1) * WSZ;
        Cout = (void*)((__bf16*)Cout_in + (size_t)z * WSZ);
    }

    __shared__ __bf16 As[64 * 32];
    __shared__ __bf16 Bs[128 * 32];
    __shared__ int s_idx[64];

    const int t    = threadIdx.x;
    const int lane = t & 63;
    const int wave = t >> 6;
    const int m0   = blockIdx.x * 64;
    const int n0   = blockIdx.y * 128;

    if constexpr (GATHER_A || DEG_VIA_IDX) {
        if (t < 64) s_idx[t] = idx[m0 + t];
        __syncthreads();
    }

    const int arow  = t >> 2;
    const int acol8 = (t & 3) * 8;
    int anode;
    if constexpr (GATHER_A) {
        anode = s_idx[arow];
    } else {
        const int rg = m0 + arow;
        anode = (rg < M) ? rg : (M - 1);
    }
    const __bf16* aptr = A + (size_t)anode * HIDDEN + acol8;

    const __bf16* bptr[2];
    #pragma unroll
    for (int r = 0; r < 2; ++r) {
        const int c = r * 256 + t;
        bptr[r] = Wt + (size_t)(n0 + (c >> 2)) * HIDDEN + (c & 3) * 8;
    }

    f32x4 acc[8];
    #pragma unroll
    for (int i = 0; i < 8; ++i) acc[i] = (f32x4){0.f, 0.f, 0.f, 0.f};

    const int wm   = wave * 16;
    const int fm   = lane & 15;
    const int quad = lane >> 4;

    for (int k0 = 0; k0 < HIDDEN; k0 += 32) {
        __syncthreads();
        load_lds16(aptr + k0, (void*)(As + (size_t)t * 8));
        #pragma unroll
        for (int r = 0; r < 2; ++r)
            load_lds16(bptr[r] + k0, (void*)(Bs + (size_t)(r * 256 + t) * 8));
        __syncthreads();

        const bf16x8 af = *(const bf16x8*)(As + (wm + fm) * 32 + quad * 8);
        bf16x8 bfr[8];
        #pragma unroll
        for (int nt = 0; nt < 8; ++nt)
            bfr[nt] = *(const bf16x8*)(Bs + (nt * 16 + fm) * 32 + quad * 8);

        #pragma unroll
        for (int nt = 0; nt < 8; ++nt)
            acc[nt] = __builtin_amdgcn_mfma_f32_16x16x32_bf16(
                af, bfr[nt], acc[nt], 0, 0, 0);
    }

    float bd[8];
    #pragma unroll
    for (int nt = 0; nt < 8; ++nt)
        bd[nt] = DEG_BIAS ? biasD[n0 + nt * 16 + fm] : 0.f;

    #pragma unroll
    for (int rg = 0; rg < 4; ++rg) {
        const int rloc = wm + quad * 4 + rg;
        const int orow = m0 + rloc;
        if (!PROD_BATCH && orow >= M) continue;
        int dnode = orow;
        if constexpr (GATHER_A || DEG_VIA_IDX) dnode = s_idx[rloc];
        float bscale = 0.f;
        if constexpr (DEG_BIAS)
            bscale = (float)(offs[dnode + 1] - offs[dnode]);
        #pragma unroll
        for (int nt = 0; nt < 8; ++nt) {
            const int col = n0 + nt * 16 + fm;
            float v = acc[nt][rg];
            if constexpr (DEG_BIAS) v += bscale * bd[nt];
            if constexpr (OUT_BF16)
                ((__bf16*)Cout)[(size_t)orow * HIDDEN + col] = (__bf16)v;
            else
                ((float*)Cout)[(size_t)orow * HIDDEN + col] = v;
        }
    }
}

// ---------------------------------------------------------------------------
// Weight prep, 12 z-slices in ONE launch:
//  z 0..8 : T[z][n][k] = (bf16)W_z[k][n]   (transpose; z = layer*3 + which)
//  z 9..10: cw_nt[z-9] = (bf16)conv_w[z-9] (straight convert)
//  z 11   : qprod — blocks (x<4, y==0): q[x][n] = sum_k cb_l[k]*W[k][n]
// ---------------------------------------------------------------------------
__global__ __launch_bounds__(256) void wconv_kernel(
    const float* __restrict__ f0_w, const float* __restrict__ f1_w,
    const float* __restrict__ conv_w, const float* __restrict__ conv_b,
    __bf16* __restrict__ wt_all, __bf16* __restrict__ cw_nt,
    float* __restrict__ q)
{
    const int z = blockIdx.z;
    const int kx = blockIdx.x * 32, nx = blockIdx.y * 32;
    const int tx = threadIdx.x, ty = threadIdx.y;

    if (z < 9) {
        const int layer = z / 3, which = z % 3;
        const float* W = ((which == 0) ? f0_w : (which == 1) ? f1_w : conv_w)
                         + (size_t)layer * WSZ;
        __bf16* T = wt_all + (size_t)z * WSZ;

        __shared__ float tile[32][33];
        for (int i = ty; i < 32; i += 8)
            tile[i][tx] = W[(size_t)(kx + i) * HIDDEN + nx + tx];
        __syncthreads();
        for (int i = ty; i < 32; i += 8)
            T[(size_t)(nx + i) * HIDDEN + kx + tx] = (__bf16)tile[tx][i];
    } else if (z < 11) {
        const int layer = z - 9;
        const float* W = conv_w + (size_t)layer * WSZ;
        __bf16* T = cw_nt + (size_t)layer * WSZ;
        for (int i = ty; i < 32; i += 8)
            T[(size_t)(kx + i) * HIDDEN + nx + tx] =
                (__bf16)W[(size_t)(kx + i) * HIDDEN + nx + tx];
    } else {
        // qprod: 4 active blocks (x<4, y==0), 256 threads each
        if (blockIdx.x >= 4 || blockIdx.y != 0) return;
        const int zq = blockIdx.x;
        const int l = zq >> 1, branch = zq & 1;
        const float* cb = conv_b + (size_t)l * HIDDEN;
        const float* W  = (branch ? f1_w : f0_w) + (size_t)(l + 1) * WSZ;
        const int n = ty * 32 + tx;
        float s = 0.f;
        #pragma unroll 4
        for (int k = 0; k < HIDDEN; ++k)
            s += cb[k] * W[(size_t)k * HIDDEN + n];
        q[(size_t)zq * HIDDEN + n] = s;
    }
}

// ---------------------------------------------------------------------------
// CSR build: histogram (+labeled-row flags) -> 2-level scan -> fill
// ---------------------------------------------------------------------------
__global__ __launch_bounds__(256) void hist_kernel(
    const int* __restrict__ dst, const int* __restrict__ pos,
    int* __restrict__ counts, int* __restrict__ flags)
{
    int e = blockIdx.x * 256 + threadIdx.x;
    if (e < N_EDGES) atomicAdd(&counts[dst[e]], 1);
    if (e < N_LABEL) flags[pos[e]] = 1;   // benign dup writes
}

__device__ __forceinline__ int block_incl_scan(int v, int* s, int t)
{
    s[t] = v; __syncthreads();
    #pragma unroll
    for (int off = 1; off < 256; off <<= 1) {
        int add = (t >= off) ? s[t - off] : 0;
        __syncthreads();
        s[t] += add;
        __syncthreads();
    }
    return s[t];
}

__global__ __launch_bounds__(256) void scan1_kernel(
    const int* __restrict__ counts, int* __restrict__ offs, int* __restrict__ bsum)
{
    __shared__ int s[256];
    const int t = threadIdx.x;
    const int i = blockIdx.x * 256 + t;
    const int v = counts[i];
    int incl = block_incl_scan(v, s, t);
    offs[i] = incl - v;
    if (t == 255) bsum[blockIdx.x] = incl;
}

__global__ __launch_bounds__(256) void scan2_kernel(
    const int* __restrict__ bsum, int* __restrict__ bbase)
{
    __shared__ int s[256];
    const int t = threadIdx.x;
    const int v = (t < SCAN_BLOCKS) ? bsum[t] : 0;
    int incl = block_incl_scan(v, s, t);
    bbase[t] = incl - v;
}

__global__ __launch_bounds__(256) void scan3_kernel(
    int* __restrict__ offs, const int* __restrict__ bbase, int* __restrict__ cursor)
{
    const int i = blockIdx.x * 256 + threadIdx.x;
    const int o = offs[i] + bbase[blockIdx.x];
    offs[i] = o;
    cursor[i] = o;
}

__global__ __launch_bounds__(256) void fill_kernel(
    const int* __restrict__ src, const int* __restrict__ dst,
    int* __restrict__ cursor, int* __restrict__ src_sorted)
{
    int e = blockIdx.x * 256 + threadIdx.x;
    if (e < N_EDGES) {
        int p = atomicAdd(&cursor[dst[e]], 1);
        src_sorted[p] = src[e];
    }
}

// ---------------------------------------------------------------------------
// Pull-mode bf16 segment sum v5 — half-wave-per-dst + software pipelining.
// (R11-verified; structural random-gather ceiling ~56-57 us: 4 structures
// all land 56-65 us, FETCH pinned ~173 MB = 7x per-XCD L2 fill.)
// ---------------------------------------------------------------------------
template <bool COMPACT>
__global__ __launch_bounds__(256) void seg_sum5_kernel(
    const __bf16* __restrict__ x0,
    const int* __restrict__ srcs,
    const int* __restrict__ offs,
    const int* __restrict__ nodelist,
    __bf16* __restrict__ out)
{
    const int t    = threadIdx.x;
    const int wave = t >> 6;
    const int lane = t & 63;
    const int half = lane >> 5;
    const int li   = lane & 31;
    const int row  = blockIdx.x * 8 + wave * 2 + half;
    const int d    = COMPACT ? nodelist[row] : row;
    const int beg  = offs[d];
    const int deg  = offs[d + 1] - beg;
    const int hb   = half * 32;

    const __bf16* xs = x0 + li * 8;

    float a[8];
    #pragma unroll
    for (int k = 0; k < 8; ++k) a[k] = 0.f;

    for (int base = 0; base < deg; base += 32) {
        const int n = min(32, deg - base);
        int vs = 0;
        if (li < n) vs = srcs[beg + base + li];
        const int nv = n & ~3;

        bf16x8 c0, c1, c2, c3;
        if (nv) {
            const int s0 = __shfl(vs, hb + 0), s1 = __shfl(vs, hb + 1);
            const int s2 = __shfl(vs, hb + 2), s3 = __shfl(vs, hb + 3);
            c0 = *(const bf16x8*)(xs + (size_t)s0 * HIDDEN);
            c1 = *(const bf16x8*)(xs + (size_t)s1 * HIDDEN);
            c2 = *(const bf16x8*)(xs + (size_t)s2 * HIDDEN);
            c3 = *(const bf16x8*)(xs + (size_t)s3 * HIDDEN);
        }
        for (int j = 4; j + 4 <= nv; j += 4) {
            const int s0 = __shfl(vs, hb + j + 0), s1 = __shfl(vs, hb + j + 1);
            const int s2 = __shfl(vs, hb + j + 2), s3 = __shfl(vs, hb + j + 3);
            const bf16x8 n0 = *(const bf16x8*)(xs + (size_t)s0 * HIDDEN);
            const bf16x8 n1 = *(const bf16x8*)(xs + (size_t)s1 * HIDDEN);
            const bf16x8 n2 = *(const bf16x8*)(xs + (size_t)s2 * HIDDEN);
            const bf16x8 n3 = *(const bf16x8*)(xs + (size_t)s3 * HIDDEN);
            #pragma unroll
            for (int k = 0; k < 8; ++k)
                a[k] += (float)c0[k] + (float)c1[k] + (float)c2[k] + (float)c3[k];
            c0 = n0; c1 = n1; c2 = n2; c3 = n3;
        }
        if (nv) {
            #pragma unroll
            for (int k = 0; k < 8; ++k)
                a[k] += (float)c0[k] + (float)c1[k] + (float)c2[k] + (float)c3[k];
        }
        for (int j = nv; j < n; ++j) {
            const int s = __shfl(vs, hb + j);
            const bf16x8 v = *(const bf16x8*)(xs + (size_t)s * HIDDEN);
            #pragma unroll
            for (int k = 0; k < 8; ++k) a[k] += (float)v[k];
        }
    }

    bf16x8 o;
    #pragma unroll
    for (int k = 0; k < 8; ++k) o[k] = (__bf16)a[k];
    *(bf16x8*)(out + (size_t)row * HIDDEN + li * 8) = o;
}

extern "C" void kernel_launch(void* const* d_in, const int* in_sizes, int n_in,
                              void* d_out, int out_size, void* d_ws, size_t ws_size,
                              hipStream_t stream)
{
    const float* x       = (const float*)d_in[0];
    const float* f0_w    = (const float*)d_in[1];
    const float* f0_b    = (const float*)d_in[2];
    const float* f1_w    = (const float*)d_in[3];
    const float* f1_b    = (const float*)d_in[4];
    const float* conv_w  = (const float*)d_in[5];
    const float* conv_b  = (const float*)d_in[6];
    const int*   edge_src = (const int*)d_in[7];
    const int*   edge_dst = (const int*)d_in[8];
    const int*   pos      = (const int*)d_in[9];
    float* out = (float*)d_out;

    const size_t buf = (size_t)N_NODES * HIDDEN;   // 12.8M elems

    char* p = (char*)d_ws;
    __bf16* bufA   = (__bf16*)p; p += buf * 2;      // 25.6 MB
    __bf16* bufB   = (__bf16*)p; p += buf * 2;      // 25.6 MB
    __bf16* s_lbl  = (__bf16*)p; p += (size_t)N_LABEL * HIDDEN * 2;  // 4 MB
    __bf16* wt_all = (__bf16*)p; p += (size_t)9 * WSZ * 2;
    __bf16* prod   = (__bf16*)p; p += (size_t)4 * WSZ * 2;
    __bf16* cw_nt  = (__bf16*)p; p += (size_t)2 * WSZ * 2;
    float*  qv     = (float*)p;  p += (size_t)4 * HIDDEN * 4;
    int* counts     = (int*)p;  p += NPAD * 4;     // reused as cursor
    int* flags      = (int*)p;  p += NPAD * 4;     // labeled-row bitmap
    int* offs       = (int*)p;  p += NPAD * 4;
    int* bsum       = (int*)p;  p += 256 * 4;
    int* bbase      = (int*)p;  p += 256 * 4;
    int* src_sorted = (int*)p;  p += (size_t)N_EDGES * 4;
    int* cursor = counts;       // counts dead after scan1

    const int edge_blocks = (N_EDGES + 255) / 256;   // 3125

    // ---- CSR build + flags (one memset covers counts+flags) ----
    hipMemsetAsync(counts, 0, 2 * NPAD * sizeof(int), stream);
    hist_kernel<<<edge_blocks, 256, 0, stream>>>(edge_dst, pos, counts, flags);
    scan1_kernel<<<SCAN_BLOCKS, 256, 0, stream>>>(counts, offs, bsum);
    scan2_kernel<<<1, 256, 0, stream>>>(bsum, bbase);
    scan3_kernel<<<SCAN_BLOCKS, 256, 0, stream>>>(offs, bbase, cursor);
    fill_kernel<<<edge_blocks, 256, 0, stream>>>(edge_src, edge_dst, cursor, src_sorted);

    // ---- weight prep: transpose (9) + straight Cw (2) + qprod, one launch ----
    wconv_kernel<<<dim3(8, 8, 12), dim3(32, 8), 0, stream>>>(
        f0_w, f1_w, conv_w, conv_b, wt_all, cw_nt, qv);

    // all 4 products prod_t[z] = (Cw_l · F_{l+1})^T in ONE batched launch
    mfma_gemm<false, false, false, true, true><<<dim3(4, 2, 4), 256, 0, stream>>>(
        wt_all, cw_nt, nullptr, prod, nullptr, nullptr, HIDDEN);

    const dim3 fused_grid(782, 2, 2);   // z=0 full (store-suppressed), z=1 label
    const dim3 lbl_grid(128, 2);

    __bf16* cur = bufA;              // S buffer (layer-0 GEMMs read x fp32)
    __bf16* tmp = bufB;

    for (int l = 0; l < N_LAYERS; ++l) {
        const float* B0 = f0_b + (size_t)l * HIDDEN;
        const float* B1 = f1_b + (size_t)l * HIDDEN;

        if (l == 0) {
            // x0 = x@F0_0+b0 (all, minus labeled) ∪ x@F1_0+b1 (labeled)
            mfma_gemm_fused<false, true><<<fused_grid, 256, 0, stream>>>(
                x, wt_all + 0 * WSZ, wt_all + 1 * WSZ,
                nullptr, nullptr, B0, B1, tmp, pos, offs, flags, N_NODES);
        } else {
            // x0 = S@(Cw·F0_l)+deg*q0+b0 ∪ S@(Cw·F1_l)+deg*q1+b1 (folded conv)
            const int z0 = (l - 1) * 2;
            mfma_gemm_fused<true, false><<<fused_grid, 256, 0, stream>>>(
                cur, prod + (size_t)z0 * WSZ, prod + (size_t)(z0 + 1) * WSZ,
                qv + (size_t)z0 * HIDDEN, qv + (size_t)(z0 + 1) * HIDDEN,
                B0, B1, tmp, pos, offs, flags, N_NODES);
        }

        if (l < N_LAYERS - 1) {
            // S = segment_sum(x0[src]) at ALL nodes (tmp -> cur)
            seg_sum5_kernel<false><<<N_NODES / 8, 256, 0, stream>>>(
                tmp, src_sorted, offs, nullptr, cur);
        } else {
            // S only at labeled dst nodes (tmp -> s_lbl, compact pos order)
            seg_sum5_kernel<true><<<N_LABEL / 8, 256, 0, stream>>>(
                tmp, src_sorted, offs, pos, s_lbl);
            // out[i] = S_lbl[i] @ Cw_2 + deg[pos[i]]*cb_2  -> d_out (fp32)
            // A sequential/compact (s_lbl), deg via idx — NOT GATHER_A (R13 bug)
            mfma_gemm<false, true, true, false, false><<<lbl_grid, 256, 0, stream>>>(
                s_lbl, wt_all + (size_t)(2 * 3 + 2) * WSZ,
                conv_b + (size_t)2 * HIDDEN, out, pos, offs, N_LABEL);
        }
    }
}